// Round 19
// baseline (335.736 us; speedup 1.0000x reference)
//
#include <hip/hip_runtime.h>
#include <math.h>

#define NN 20000
#define NE 160000
#define DH 128

typedef _Float16 f16;
typedef f16 f16x2 __attribute__((ext_vector_type(2)));
typedef f16 f16x4 __attribute__((ext_vector_type(4)));
typedef f16 f16x8 __attribute__((ext_vector_type(8)));
typedef float f32x4 __attribute__((ext_vector_type(4)));
typedef unsigned int uint32;
typedef unsigned char u8;

// ---------------- prep: fused x->f16 convert + degree count ----------------
__global__ void conv_count_kernel(const float* __restrict__ X, f16* __restrict__ XH,
                                  int n4, const int* __restrict__ edst,
                                  int* __restrict__ deg, int ne) {
  int i = blockIdx.x * blockDim.x + threadIdx.x;
  if (i < n4) {
    float4 v = *(const float4*)(X + (size_t)i * 4);
    f16x4 o = {(f16)v.x, (f16)v.y, (f16)v.z, (f16)v.w};
    *(f16x4*)(XH + (size_t)i * 4) = o;
  }
  if (i < ne) atomicAdd(&deg[edst[i]], 1);
}

// ---------------- CSR build (2-phase) ----------------
__global__ __launch_bounds__(1024) void csr_p1(const int* __restrict__ deg,
                                               int* __restrict__ rowstart,
                                               int* __restrict__ bsum,
                                               int* __restrict__ ghist, int n) {
  __shared__ int wsum[16];
  __shared__ int lhist[64];
  const int tid = threadIdx.x;
  const int lane = tid & 63, w = tid >> 6;
  if (tid < 64) lhist[tid] = 0;
  __syncthreads();
  int i = blockIdx.x * 1024 + tid;
  int d = (i < n) ? deg[i] : 0;
  if (i < n) atomicAdd(&lhist[d < 63 ? d : 63], 1);
  int v = d;
#pragma unroll
  for (int off = 1; off < 64; off <<= 1) {
    int u = __shfl_up(v, off, 64);
    if (lane >= off) v += u;
  }
  if (lane == 63) wsum[w] = v;
  __syncthreads();
  if (w == 0) {
    int t = (lane < 16) ? wsum[lane] : 0;
#pragma unroll
    for (int off = 1; off < 16; off <<= 1) {
      int u = __shfl_up(t, off, 64);
      if (lane >= off) t += u;
    }
    if (lane < 16) wsum[lane] = t;
  }
  __syncthreads();
  int add = (w > 0 ? wsum[w - 1] : 0);
  if (i < n) rowstart[i + 1] = v + add;
  if (tid == 0) bsum[blockIdx.x] = wsum[15];
  if (tid < 64) ghist[blockIdx.x * 64 + tid] = lhist[tid];
}

__global__ __launch_bounds__(1024) void csr_p3(const int* __restrict__ deg,
                                               int* __restrict__ rowstart,
                                               const int* __restrict__ bsum,
                                               const int* __restrict__ ghist,
                                               int* __restrict__ perm, int n, int nb) {
  __shared__ int lcur[64];
  __shared__ int base[64];
  __shared__ int radd_s;
  const int tid = threadIdx.x;
  if (tid < 64) {
    lcur[tid] = 0;
    int pre = 0, tot = 0;
    for (int b = 0; b < nb; b++) {
      int v = ghist[b * 64 + tid];
      pre += (b < (int)blockIdx.x) ? v : 0;
      tot += v;
    }
    int incl = tot;
#pragma unroll
    for (int off = 1; off < 64; off <<= 1) {
      int u = __shfl_up(incl, off, 64);
      if (tid >= off) incl += u;
    }
    base[tid] = (n - incl) + pre;  // descending bucket start + within-bin prefix
  }
  if (tid == 0) {
    int r = 0;
    for (int b = 0; b < (int)blockIdx.x; b++) r += bsum[b];
    radd_s = r;
  }
  __syncthreads();
  int i = blockIdx.x * 1024 + tid;
  if (i < n) {
    rowstart[i + 1] += radd_s;
    int d = deg[i];
    int b = d < 63 ? d : 63;
    int pos = atomicAdd(&lcur[b], 1);
    perm[base[b] + pos] = i;
  }
  if (blockIdx.x == 0 && tid == 0) rowstart[0] = 0;
}

__global__ void scatter_kernel(const int* __restrict__ src, const int* __restrict__ dstp,
                               const int* __restrict__ rowstart, int* __restrict__ cursor,
                               int* __restrict__ csr, int n) {
  int i = blockIdx.x * blockDim.x + threadIdx.x;
  if (i < n) {
    int d = dstp[i];
    int pos = atomicAdd(&cursor[d], 1);
    csr[rowstart[d] + pos] = src[i];
  }
}

// one 16-lane subgroup per row; 16-element bitonic network.
__global__ void sort_kernel(const int* __restrict__ rowstart, int* __restrict__ csr,
                            const int* __restrict__ perm, int n) {
  int idx = blockIdx.x * blockDim.x + threadIdx.x;
  int sub = idx >> 4;
  int u = idx & 15;
  if (sub >= n) return;
  int i = perm[sub];
  int a = rowstart[i], b = rowstart[i + 1];
  int d = b - a;
  if (d <= 1) return;
  if (d <= 16) {
    int v = (u < d) ? csr[a + u] : 0x7FFFFFFF;
#pragma unroll
    for (int k = 2; k <= 16; k <<= 1) {
#pragma unroll
      for (int j = 16; j > 0; j >>= 1) {
        if (j > (k >> 1)) continue;
        int o = __shfl_xor(v, j, 64);
        bool takeMin = (((u & k) == 0) == ((u & j) == 0));
        v = takeMin ? (v < o ? v : o) : (v > o ? v : o);
      }
    }
    if (u < d) csr[a + u] = v;
  } else if (u == 0) {
    for (int j = a + 1; j < b; j++) {
      int v = csr[j];
      int k = j - 1;
      while (k >= a && csr[k] > v) { csr[k + 1] = csr[k]; k--; }
      csr[k + 1] = v;
    }
  }
}

// ---------------- weights: W [128][HC] f32 -> WT [HC][128] f16 ----------------
__global__ __launch_bounds__(256) void transconv_all(
    const float* __restrict__ W0, const float* __restrict__ W1,
    const float* __restrict__ W2, const float* __restrict__ W3,
    const float* __restrict__ W4, const float* __restrict__ W5,
    f16* O0, f16* O1, f16* O2, f16* O3, f16* O4, f16* O5) {
  const float* W; f16* O; int HC;
  switch (blockIdx.z) {
    case 0: W = W0; O = O0; HC = 1024; break;
    case 1: W = W1; O = O1; HC = 1024; break;
    case 2: W = W2; O = O2; HC = 1024; break;
    case 3: W = W3; O = O3; HC = 1024; break;
    case 4: W = W4; O = O4; HC = 512; break;
    default: W = W5; O = O5; HC = 512; break;
  }
  int c0 = blockIdx.x * 32;
  if (c0 >= HC) return;
  __shared__ float t[32][33];
  int k0 = blockIdx.y * 32;
  int tx = threadIdx.x & 31, ty = threadIdx.x >> 5;  // 32 x 8
#pragma unroll
  for (int j = 0; j < 4; j++) {
    int k = k0 + ty + j * 8;
    t[ty + j * 8][tx] = W[(size_t)k * HC + c0 + tx];
  }
  __syncthreads();
#pragma unroll
  for (int j = 0; j < 4; j++) {
    int c = c0 + ty + j * 8;
    O[(size_t)c * 128 + k0 + tx] = (f16)t[tx][ty + j * 8];
  }
}

// ---------------- GEMM core (re-tiled for occupancy, R19) ----------------
// R18 lesson: 46.6us at <10% util on ALL pipes, occ 27%, invariant under
// epilogue changes -> latency-bound core. Fix: wave tile 64x32 (acc[4][2]=32
// VGPR, was 64), block = 128 rows x 64 cols, 2x grid -> ~5 blocks/CU resident.
// Same per-element MFMA order -> bitwise-identical C.

template <int YB>  // YB = Nout/64 column blocks (nx*YB % 8 == 0)
__device__ __forceinline__ void gemm_core(const f16* __restrict__ A,
                                          const f16* __restrict__ BT, int M,
                                          int& bx, int& by, f32x4 (&acc)[4][2]) {
  const int nx = (M + 127) / 128;
  const int chunk = nx * YB / 8;
  const int bid = blockIdx.x;
  const int p = (bid % 8) * chunk + bid / 8;
  bx = p / YB;
  by = p % YB;

  const int w = threadIdx.x >> 6, lane = threadIdx.x & 63;
  const int wm = w >> 1, wn = w & 1;
  const int row0 = bx * 128 + wm * 64;
  const int col0 = by * 64 + wn * 32;
  const int lr = lane & 15, lk = (lane >> 4) * 8;

  const f16* Arow[4];
  const f16* Brow[2];
#pragma unroll
  for (int m = 0; m < 4; m++) {
    int r = row0 + m * 16 + lr;
    r = r < M ? r : M - 1;
    Arow[m] = A + (size_t)r * 128 + lk;
  }
#pragma unroll
  for (int n = 0; n < 2; n++) {
    int c = col0 + n * 16 + lr;
    Brow[n] = BT + (size_t)c * 128 + lk;
  }
#pragma unroll
  for (int ks = 0; ks < 4; ks++) {
    f16x8 a[4], b[2];
#pragma unroll
    for (int m = 0; m < 4; m++) a[m] = *(const f16x8*)(Arow[m] + ks * 32);
#pragma unroll
    for (int n = 0; n < 2; n++) b[n] = *(const f16x8*)(Brow[n] + ks * 32);
#pragma unroll
    for (int m = 0; m < 4; m++)
#pragma unroll
      for (int n = 0; n < 2; n++)
        acc[m][n] = __builtin_amdgcn_mfma_f32_16x16x32_f16(a[m], b[n], acc[m][n], 0, 0, 0);
  }
}

// f16-out GEMM (layer 3): block tile 128x64, two-pass LDS epilogue
template <int YB>
__global__ __launch_bounds__(256) void gemm_f16(const f16* __restrict__ A,
                                                const f16* __restrict__ BT,
                                                f16* __restrict__ C, int M, int Nout) {
  __shared__ f16 ct[64][72];
  int bx, by;
  f32x4 acc[4][2] = {};
  gemm_core<YB>(A, BT, M, bx, by, acc);

  const int w = threadIdx.x >> 6, lane = threadIdx.x & 63;
  const int wm = w >> 1, wn = w & 1;
  const int lr = lane & 15;
  const int lcol = wn * 32;
  const int t = threadIdx.x;
  const int rowblk = bx * 128, colblk = by * 64;

#pragma unroll
  for (int half = 0; half < 2; half++) {
    if (wm == half) {
#pragma unroll
      for (int m = 0; m < 4; m++) {
        int rbase = m * 16 + (lane >> 4) * 4;
#pragma unroll
        for (int r = 0; r < 4; r++)
#pragma unroll
          for (int n = 0; n < 2; n++)
            ct[rbase + r][lcol + n * 16 + lr] = (f16)acc[m][n][r];
      }
    }
    __syncthreads();
    // 8 threads/row x 16B: 128B per 64-col f16 row
#pragma unroll
    for (int rr = (t >> 3); rr < 64; rr += 32) {
      int gr = rowblk + half * 64 + rr;
      if (gr < M) {
        int cidx = (t & 7) * 8;
        uint4 v = *(const uint4*)(&ct[rr][cidx]);
        *(uint4*)(C + (size_t)gr * Nout + colblk + cidx) = v;
      }
    }
    __syncthreads();
  }
}

// fp8-out GEMM (layers 1-2): whole C row fp8-e4m3, 2048 B rows
template <int YB>
__global__ __launch_bounds__(256) void gemm_f8(const f16* __restrict__ A,
                                               const f16* __restrict__ BT,
                                               u8* __restrict__ C8, int M) {
  __shared__ f16 ct[64][72];
  int bx, by;
  f32x4 acc[4][2] = {};
  gemm_core<YB>(A, BT, M, bx, by, acc);

  const int w = threadIdx.x >> 6, lane = threadIdx.x & 63;
  const int wm = w >> 1, wn = w & 1;
  const int lr = lane & 15;
  const int lcol = wn * 32;
  const int t = threadIdx.x;
  const int rowblk = bx * 128, colblk = by * 64;

#pragma unroll
  for (int half = 0; half < 2; half++) {
    if (wm == half) {
#pragma unroll
      for (int m = 0; m < 4; m++) {
        int rbase = m * 16 + (lane >> 4) * 4;
#pragma unroll
        for (int r = 0; r < 4; r++)
#pragma unroll
          for (int n = 0; n < 2; n++)
            ct[rbase + r][lcol + n * 16 + lr] = (f16)acc[m][n][r];
      }
    }
    __syncthreads();
    // 8 threads/row x 8B fp8: 64B per 64-col row
#pragma unroll
    for (int rr = (t >> 3); rr < 64; rr += 32) {
      int gr = rowblk + half * 64 + rr;
      if (gr < M) {
        int cidx = (t & 7) * 8;
        f16x8 v = *(const f16x8*)(&ct[rr][cidx]);
        int lo = __builtin_amdgcn_cvt_pk_fp8_f32((float)v[0], (float)v[1], 0, false);
        lo = __builtin_amdgcn_cvt_pk_fp8_f32((float)v[2], (float)v[3], lo, true);
        int hi = __builtin_amdgcn_cvt_pk_fp8_f32((float)v[4], (float)v[5], 0, false);
        hi = __builtin_amdgcn_cvt_pk_fp8_f32((float)v[6], (float)v[7], hi, true);
        uint2 o;
        o.x = (uint32)lo;
        o.y = (uint32)hi;
        *(uint2*)(C8 + (size_t)gr * 2048 + colblk + cidx) = o;
      }
    }
    __syncthreads();
  }
}

// ---------------- fused GATv2 aggregation ----------------
// NOTE (R14): persistent grid-stride agg REGRESSED; keep 1-shot blocks.
// NOTE (R11): 8-deep masked merge REGRESSED; keep 4-deep + scalar tail.
struct LV { f16x2 v[4]; };

__device__ __forceinline__ f16x2 bc2(uint32 x) { return __builtin_bit_cast(f16x2, x); }

__device__ __forceinline__ LV load8(const char* __restrict__ base, uint32 off) {
  uint4 r = *(const uint4*)(base + off);
  LV o;
  o.v[0] = bc2(r.x); o.v[1] = bc2(r.y); o.v[2] = bc2(r.z); o.v[3] = bc2(r.w);
  return o;
}

// fp8-e4m3 gather: 8 bytes -> 8 f16 via HW cvt (exact embeddings).
__device__ __forceinline__ LV load8_f8(const char* __restrict__ base, uint32 off) {
  uint2 w = *(const uint2*)(base + off);
  auto a = __builtin_amdgcn_cvt_pk_f32_fp8((int)w.x, false);
  auto b = __builtin_amdgcn_cvt_pk_f32_fp8((int)w.x, true);
  auto c = __builtin_amdgcn_cvt_pk_f32_fp8((int)w.y, false);
  auto d = __builtin_amdgcn_cvt_pk_f32_fp8((int)w.y, true);
  LV o;
  o.v[0] = __builtin_bit_cast(f16x2, __builtin_amdgcn_cvt_pkrtz(a[0], a[1]));
  o.v[1] = __builtin_bit_cast(f16x2, __builtin_amdgcn_cvt_pkrtz(b[0], b[1]));
  o.v[2] = __builtin_bit_cast(f16x2, __builtin_amdgcn_cvt_pkrtz(c[0], c[1]));
  o.v[3] = __builtin_bit_cast(f16x2, __builtin_amdgcn_cvt_pkrtz(d[0], d[1]));
  return o;
}

template <bool F8>
__device__ __forceinline__ LV loadxl(const char* __restrict__ p, uint32 off) {
  if constexpr (F8) return load8_f8(p, off);
  else return load8(p, off);
}

__device__ __forceinline__ f16x2 leaky2(f16x2 z) {
  f16x2 zs = z * (f16)0.2f;
  return __builtin_elementwise_max(z, zs);
}

__device__ __forceinline__ float edot(const LV& x, const f16x2* xr2, const f16x2* att2) {
  float ea = 0.f, eb = 0.f;
  ea = __builtin_amdgcn_fdot2(leaky2(x.v[0] + xr2[0]), att2[0], ea, false);
  eb = __builtin_amdgcn_fdot2(leaky2(x.v[1] + xr2[1]), att2[1], eb, false);
  ea = __builtin_amdgcn_fdot2(leaky2(x.v[2] + xr2[2]), att2[2], ea, false);
  eb = __builtin_amdgcn_fdot2(leaky2(x.v[3] + xr2[3]), att2[3], eb, false);
  return ea + eb;
}

template <int PAT>
__device__ __forceinline__ float swz(float x) {
  return __int_as_float(__builtin_amdgcn_ds_swizzle(__float_as_int(x), PAT));
}

__device__ __forceinline__ void red16x4(float& a, float& b, float& c, float& d) {
  a += swz<0x041F>(a); b += swz<0x041F>(b); c += swz<0x041F>(c); d += swz<0x041F>(d);
  a += swz<0x081F>(a); b += swz<0x081F>(b); c += swz<0x081F>(c); d += swz<0x081F>(d);
  a += swz<0x101F>(a); b += swz<0x101F>(b); c += swz<0x101F>(c); d += swz<0x101F>(d);
  a += swz<0x201F>(a); b += swz<0x201F>(b); c += swz<0x201F>(c); d += swz<0x201F>(d);
}
__device__ __forceinline__ float red16(float a) {
  a += swz<0x041F>(a);
  a += swz<0x081F>(a);
  a += swz<0x101F>(a);
  a += swz<0x201F>(a);
  return a;
}

// H heads; DG dst-groups/block; F8: xl fp8; XR8: xr fp8; LGXL/LGXR log2 strides.
template <int H, int DG, bool RELU, bool WF32, bool F8, bool XR8, int LGXL, int LGXR>
__global__ __launch_bounds__(H * DG * 64) void agg_kernel(
    const f16* __restrict__ h_in, const char* __restrict__ xlp,
    const char* __restrict__ xrp, const float* __restrict__ att,
    const float* __restrict__ bias, const int* __restrict__ csr,
    const int* __restrict__ rowstart, const int* __restrict__ perm,
    float* __restrict__ h_out, f16* __restrict__ hh) {
  __shared__ float headout[H][4 * DG][DH];
  __shared__ int nodes[4 * DG];
  const int wv = threadIdx.x >> 6;
  const int h = wv & (H - 1);
  const int dg = wv / H;
  const int lane = threadIdx.x & 63;
  const int g = lane >> 4, u = lane & 15;
  const int c0 = u * 8;
  if (threadIdx.x < 4 * DG) nodes[threadIdx.x] = perm[blockIdx.x * 4 * DG + threadIdx.x];
  const int dst = perm[blockIdx.x * 4 * DG + dg * 4 + g];
  const uint32 loff_xl = (uint32)(h * DH + c0) << (F8 ? 0 : 1);
  const uint32 loff_xr = (uint32)(h * DH + c0) << (XR8 ? 0 : 1);

  f16x2 att2[4], xr2[4];
  {
    const float* ap = att + h * DH + c0;
    float a0[8];
    *(float4*)a0 = *(const float4*)ap;
    *(float4*)(a0 + 4) = *(const float4*)(ap + 4);
#pragma unroll
    for (int q = 0; q < 4; q++) att2[q] = f16x2{(f16)a0[2 * q], (f16)a0[2 * q + 1]};
    LV xrv = loadxl<XR8>(xrp, ((uint32)dst << LGXR) + loff_xr);
#pragma unroll
    for (int q = 0; q < 4; q++) xr2[q] = xrv.v[q];
  }

  const int js = rowstart[dst], je = rowstart[dst + 1];

  // self loop seed
  float m, s;
  f16x2 acc[4];
  {
    LV xv = loadxl<F8>(xlp, ((uint32)dst << LGXL) + loff_xl);
    m = red16(edot(xv, xr2, att2));
    s = 1.f;
#pragma unroll
    for (int q = 0; q < 4; q++) acc[q] = xv.v[q];
  }

  // 4-deep prefetch over CSR row (indices clamped to je-1)
  LV pf0, pf1, pf2, pf3;
  {
    int ja = js < je ? js : je - 1;
    int jb = js + 1 < je ? js + 1 : je - 1;
    int jc = js + 2 < je ? js + 2 : je - 1;
    int jd = js + 3 < je ? js + 3 : je - 1;
    if (js < je) {
      pf0 = loadxl<F8>(xlp, ((uint32)csr[ja] << LGXL) + loff_xl);
      pf1 = loadxl<F8>(xlp, ((uint32)csr[jb] << LGXL) + loff_xl);
      pf2 = loadxl<F8>(xlp, ((uint32)csr[jc] << LGXL) + loff_xl);
      pf3 = loadxl<F8>(xlp, ((uint32)csr[jd] << LGXL) + loff_xl);
    }
  }

  int j = js;
  for (; j + 3 < je; j += 4) {
    LV cv0 = pf0, cv1 = pf1, cv2 = pf2, cv3 = pf3;
    int ja = j + 4 < je ? j + 4 : je - 1;
    int jb = j + 5 < je ? j + 5 : je - 1;
    int jc = j + 6 < je ? j + 6 : je - 1;
    int jd = j + 7 < je ? j + 7 : je - 1;
    pf0 = loadxl<F8>(xlp, ((uint32)csr[ja] << LGXL) + loff_xl);
    pf1 = loadxl<F8>(xlp, ((uint32)csr[jb] << LGXL) + loff_xl);
    pf2 = loadxl<F8>(xlp, ((uint32)csr[jc] << LGXL) + loff_xl);
    pf3 = loadxl<F8>(xlp, ((uint32)csr[jd] << LGXL) + loff_xl);

    float e0 = edot(cv0, xr2, att2);
    float e1 = edot(cv1, xr2, att2);
    float e2 = edot(cv2, xr2, att2);
    float e3 = edot(cv3, xr2, att2);
    red16x4(e0, e1, e2, e3);

    float mn = fmaxf(fmaxf(fmaxf(m, e0), fmaxf(e1, e2)), e3);
    float a = __expf(m - mn);
    float p0 = __expf(e0 - mn);
    float p1 = __expf(e1 - mn);
    float p2 = __expf(e2 - mn);
    float p3 = __expf(e3 - mn);
    s = s * a + ((p0 + p1) + (p2 + p3));
    f16 ah = (f16)a, g0 = (f16)p0, g1 = (f16)p1, g2 = (f16)p2, g3 = (f16)p3;
    f16x2 a2 = {ah, ah}, q0 = {g0, g0}, q1 = {g1, g1}, q2 = {g2, g2}, q3 = {g3, g3};
#pragma unroll
    for (int q = 0; q < 4; q++) {
      f16x2 t = acc[q] * a2;
      t = cv0.v[q] * q0 + t;
      t = cv1.v[q] * q1 + t;
      t = cv2.v[q] * q2 + t;
      t = cv3.v[q] * q3 + t;
      acc[q] = t;
    }
    m = mn;
  }
  // tail: consume remaining prefetched edges one at a time
  for (int t = 0; j < je; j++, t++) {
    LV cv = (t == 0) ? pf0 : (t == 1) ? pf1 : pf2;
    float e = red16(edot(cv, xr2, att2));
    float mn = fmaxf(m, e);
    float a = __expf(m - mn);
    float p = __expf(e - mn);
    s = s * a + p;
    f16 ah = (f16)a, gh = (f16)p;
    f16x2 a2 = {ah, ah}, p2 = {gh, gh};
#pragma unroll
    for (int q = 0; q < 4; q++) acc[q] = acc[q] * a2 + cv.v[q] * p2;
    m = mn;
  }

  float inv = 1.f / s;
#pragma unroll
  for (int q = 0; q < 4; q++) {
    headout[h][dg * 4 + g][c0 + 2 * q] = (float)acc[q][0] * inv;
    headout[h][dg * 4 + g][c0 + 2 * q + 1] = (float)acc[q][1] * inv;
  }
  __syncthreads();
  for (int t = threadIdx.x; t < 4 * DG * DH; t += H * DG * 64) {
    int d = t >> 7, c = t & 127;
    float sum = 0.f;
#pragma unroll
    for (int q = 0; q < H; q++) sum += headout[q][d][c];
    float r = sum * (1.f / H) + bias[c];
    if (RELU) r = fmaxf(r, 0.f);
    int node = nodes[d];
    float o = r + (float)h_in[(size_t)node * DH + c];
    if (WF32) h_out[(size_t)node * DH + c] = o;
    else hh[(size_t)node * DH + c] = (f16)o;
  }
}

extern "C" void kernel_launch(void* const* d_in, const int* in_sizes, int n_in,
                              void* d_out, int out_size, void* d_ws, size_t ws_size,
                              hipStream_t stream) {
  const float* x = (const float*)d_in[0];
  const int* ei = (const int*)d_in[1];
  const float* Wl1 = (const float*)d_in[2];
  const float* Wr1 = (const float*)d_in[3];
  const float* att1 = (const float*)d_in[4];
  const float* b1 = (const float*)d_in[5];
  const float* Wl2 = (const float*)d_in[6];
  const float* Wr2 = (const float*)d_in[7];
  const float* att2 = (const float*)d_in[8];
  const float* b2 = (const float*)d_in[9];
  const float* Wl3 = (const float*)d_in[10];
  const float* Wr3 = (const float*)d_in[11];
  const float* att3 = (const float*)d_in[12];
  const float* b3 = (const float*)d_in[13];
  float* out = (float*)d_out;

  char* p = (char*)d_ws;
  f16* xlr = (f16*)p; p += (size_t)NN * 2048 * 2;   // layer-3 f16 buffer
  u8* xl8  = (u8*)p;  p += (size_t)NN * 2048;       // layers 1-2 fp8 buffer (xl|xr)
  f16* xh  = (f16*)p; p += (size_t)NN * DH * 2;
  f16* h1h = (f16*)p; p += (size_t)NN * DH * 2;
  f16* h2h = (f16*)p; p += (size_t)NN * DH * 2;
  f16* WT1 = (f16*)p; p += (size_t)2048 * 128 * 2;
  f16* WT2 = (f16*)p; p += (size_t)2048 * 128 * 2;
  f16* WT3 = (f16*)p; p += (size_t)1024 * 128 * 2;
  int* deg      = (int*)p; p += (size_t)NN * 4;
  int* cursor   = (int*)p; p += (size_t)NN * 4;
  int* rowstart = (int*)p; p += (size_t)(NN + 1) * 4;
  int* perm     = (int*)p; p += (size_t)NN * 4;
  int* bsum     = (int*)p; p += (size_t)32 * 4;
  int* ghist    = (int*)p; p += (size_t)20 * 64 * 4;
  int* csr      = (int*)p;

  const int* esrc = ei;
  const int* edst = ei + NE;

  const int nbc = (NN + 1023) / 1024;  // 20 CSR-build blocks

  hipMemsetAsync(deg, 0, sizeof(int) * 2 * NN, stream);  // deg + cursor
  conv_count_kernel<<<(NN * DH / 4 + 255) / 256, 256, 0, stream>>>(
      x, xh, NN * DH / 4, edst, deg, NE);
  csr_p1<<<nbc, 1024, 0, stream>>>(deg, rowstart, bsum, ghist, NN);
  csr_p3<<<nbc, 1024, 0, stream>>>(deg, rowstart, bsum, ghist, perm, NN, nbc);
  scatter_kernel<<<(NE + 255) / 256, 256, 0, stream>>>(esrc, edst, rowstart, cursor, csr, NE);
  sort_kernel<<<(NN * 16 + 255) / 256, 256, 0, stream>>>(rowstart, csr, perm, NN);
  transconv_all<<<dim3(32, 4, 6), 256, 0, stream>>>(
      Wl1, Wr1, Wl2, Wr2, Wl3, Wr3,
      WT1, WT1 + (size_t)1024 * 128, WT2, WT2 + (size_t)1024 * 128,
      WT3, WT3 + (size_t)512 * 128);

  const int nx = (NN + 127) / 128;  // 157

  // layer 1: C fully fp8 (xl cols 0-1023, xr cols 1024-2047; 2048 B rows)
  gemm_f8<32><<<nx * 32, 256, 0, stream>>>(xh, WT1, xl8, NN);
  agg_kernel<8, 1, true, false, true, true, 11, 11><<<NN / 4, 512, 0, stream>>>(
      xh, (const char*)xl8, (const char*)xl8 + 1024, att1, b1, csr, rowstart,
      perm, nullptr, h1h);
  // layer 2: same scheme
  gemm_f8<32><<<nx * 32, 256, 0, stream>>>(h1h, WT2, xl8, NN);
  agg_kernel<8, 1, true, false, true, true, 11, 11><<<NN / 4, 512, 0, stream>>>(
      h1h, (const char*)xl8, (const char*)xl8 + 1024, att2, b2, csr, rowstart,
      perm, nullptr, h2h);
  // layer 3: f16 (stride 2048 B; xr at +1024 B), output f32 + residual
  gemm_f16<16><<<nx * 16, 256, 0, stream>>>(h2h, WT3, xlr, NN, 1024);
  agg_kernel<4, 2, false, true, false, false, 11, 11><<<NN / 8, 512, 0, stream>>>(
      h2h, (const char*)xlr, (const char*)xlr + 1024, att3, b3, csr, rowstart,
      perm, out, nullptr);
}

// Round 20
// 324.650 us; speedup vs baseline: 1.0341x; 1.0341x over previous
//
#include <hip/hip_runtime.h>
#include <math.h>

#define NN 20000
#define NE 160000
#define DH 128

typedef _Float16 f16;
typedef f16 f16x2 __attribute__((ext_vector_type(2)));
typedef f16 f16x4 __attribute__((ext_vector_type(4)));
typedef f16 f16x8 __attribute__((ext_vector_type(8)));
typedef float f32x4 __attribute__((ext_vector_type(4)));
typedef unsigned int uint32;
typedef unsigned char u8;

// ---------------- prep: fused x->f16 convert + degree count ----------------
__global__ void conv_count_kernel(const float* __restrict__ X, f16* __restrict__ XH,
                                  int n4, const int* __restrict__ edst,
                                  int* __restrict__ deg, int ne) {
  int i = blockIdx.x * blockDim.x + threadIdx.x;
  if (i < n4) {
    float4 v = *(const float4*)(X + (size_t)i * 4);
    f16x4 o = {(f16)v.x, (f16)v.y, (f16)v.z, (f16)v.w};
    *(f16x4*)(XH + (size_t)i * 4) = o;
  }
  if (i < ne) atomicAdd(&deg[edst[i]], 1);
}

// ---------------- CSR build (2-phase) ----------------
__global__ __launch_bounds__(1024) void csr_p1(const int* __restrict__ deg,
                                               int* __restrict__ rowstart,
                                               int* __restrict__ bsum,
                                               int* __restrict__ ghist, int n) {
  __shared__ int wsum[16];
  __shared__ int lhist[64];
  const int tid = threadIdx.x;
  const int lane = tid & 63, w = tid >> 6;
  if (tid < 64) lhist[tid] = 0;
  __syncthreads();
  int i = blockIdx.x * 1024 + tid;
  int d = (i < n) ? deg[i] : 0;
  if (i < n) atomicAdd(&lhist[d < 63 ? d : 63], 1);
  int v = d;
#pragma unroll
  for (int off = 1; off < 64; off <<= 1) {
    int u = __shfl_up(v, off, 64);
    if (lane >= off) v += u;
  }
  if (lane == 63) wsum[w] = v;
  __syncthreads();
  if (w == 0) {
    int t = (lane < 16) ? wsum[lane] : 0;
#pragma unroll
    for (int off = 1; off < 16; off <<= 1) {
      int u = __shfl_up(t, off, 64);
      if (lane >= off) t += u;
    }
    if (lane < 16) wsum[lane] = t;
  }
  __syncthreads();
  int add = (w > 0 ? wsum[w - 1] : 0);
  if (i < n) rowstart[i + 1] = v + add;
  if (tid == 0) bsum[blockIdx.x] = wsum[15];
  if (tid < 64) ghist[blockIdx.x * 64 + tid] = lhist[tid];
}

__global__ __launch_bounds__(1024) void csr_p3(const int* __restrict__ deg,
                                               int* __restrict__ rowstart,
                                               const int* __restrict__ bsum,
                                               const int* __restrict__ ghist,
                                               int* __restrict__ perm, int n, int nb) {
  __shared__ int lcur[64];
  __shared__ int base[64];
  __shared__ int radd_s;
  const int tid = threadIdx.x;
  if (tid < 64) {
    lcur[tid] = 0;
    int pre = 0, tot = 0;
    for (int b = 0; b < nb; b++) {
      int v = ghist[b * 64 + tid];
      pre += (b < (int)blockIdx.x) ? v : 0;
      tot += v;
    }
    int incl = tot;
#pragma unroll
    for (int off = 1; off < 64; off <<= 1) {
      int u = __shfl_up(incl, off, 64);
      if (tid >= off) incl += u;
    }
    base[tid] = (n - incl) + pre;  // descending bucket start + within-bin prefix
  }
  if (tid == 0) {
    int r = 0;
    for (int b = 0; b < (int)blockIdx.x; b++) r += bsum[b];
    radd_s = r;
  }
  __syncthreads();
  int i = blockIdx.x * 1024 + tid;
  if (i < n) {
    rowstart[i + 1] += radd_s;
    int d = deg[i];
    int b = d < 63 ? d : 63;
    int pos = atomicAdd(&lcur[b], 1);
    perm[base[b] + pos] = i;
  }
  if (blockIdx.x == 0 && tid == 0) rowstart[0] = 0;
}

__global__ void scatter_kernel(const int* __restrict__ src, const int* __restrict__ dstp,
                               const int* __restrict__ rowstart, int* __restrict__ cursor,
                               int* __restrict__ csr, int n) {
  int i = blockIdx.x * blockDim.x + threadIdx.x;
  if (i < n) {
    int d = dstp[i];
    int pos = atomicAdd(&cursor[d], 1);
    csr[rowstart[d] + pos] = src[i];
  }
}

// one 16-lane subgroup per row; 16-element bitonic network.
__global__ void sort_kernel(const int* __restrict__ rowstart, int* __restrict__ csr,
                            const int* __restrict__ perm, int n) {
  int idx = blockIdx.x * blockDim.x + threadIdx.x;
  int sub = idx >> 4;
  int u = idx & 15;
  if (sub >= n) return;
  int i = perm[sub];
  int a = rowstart[i], b = rowstart[i + 1];
  int d = b - a;
  if (d <= 1) return;
  if (d <= 16) {
    int v = (u < d) ? csr[a + u] : 0x7FFFFFFF;
#pragma unroll
    for (int k = 2; k <= 16; k <<= 1) {
#pragma unroll
      for (int j = 16; j > 0; j >>= 1) {
        if (j > (k >> 1)) continue;
        int o = __shfl_xor(v, j, 64);
        bool takeMin = (((u & k) == 0) == ((u & j) == 0));
        v = takeMin ? (v < o ? v : o) : (v > o ? v : o);
      }
    }
    if (u < d) csr[a + u] = v;
  } else if (u == 0) {
    for (int j = a + 1; j < b; j++) {
      int v = csr[j];
      int k = j - 1;
      while (k >= a && csr[k] > v) { csr[k + 1] = csr[k]; k--; }
      csr[k + 1] = v;
    }
  }
}

// ---------------- weights: W [128][HC] f32 -> WT [HC][128] f16 ----------------
__global__ __launch_bounds__(256) void transconv_all(
    const float* __restrict__ W0, const float* __restrict__ W1,
    const float* __restrict__ W2, const float* __restrict__ W3,
    const float* __restrict__ W4, const float* __restrict__ W5,
    f16* O0, f16* O1, f16* O2, f16* O3, f16* O4, f16* O5) {
  const float* W; f16* O; int HC;
  switch (blockIdx.z) {
    case 0: W = W0; O = O0; HC = 1024; break;
    case 1: W = W1; O = O1; HC = 1024; break;
    case 2: W = W2; O = O2; HC = 1024; break;
    case 3: W = W3; O = O3; HC = 1024; break;
    case 4: W = W4; O = O4; HC = 512; break;
    default: W = W5; O = O5; HC = 512; break;
  }
  int c0 = blockIdx.x * 32;
  if (c0 >= HC) return;
  __shared__ float t[32][33];
  int k0 = blockIdx.y * 32;
  int tx = threadIdx.x & 31, ty = threadIdx.x >> 5;  // 32 x 8
#pragma unroll
  for (int j = 0; j < 4; j++) {
    int k = k0 + ty + j * 8;
    t[ty + j * 8][tx] = W[(size_t)k * HC + c0 + tx];
  }
  __syncthreads();
#pragma unroll
  for (int j = 0; j < 4; j++) {
    int c = c0 + ty + j * 8;
    O[(size_t)c * 128 + k0 + tx] = (f16)t[tx][ty + j * 8];
  }
}

// ---------------- LDS-staged f16 MFMA GEMM (R20) ----------------
// R19 lesson: fragment-direct global loads are 16-row gathers (each load
// instr = ~16 L2 transactions); time scaled with load-instr count, every pipe
// <12% busy. Fix: coalesced cooperative staging of A-tile + BT-tile into LDS
// (pad row to 130 f16 -> fragment ds_reads 2 lanes/bank = free), identical
// MFMA order -> bitwise-identical C. Epilogue reuses A-tile LDS (two-pass).
template <int YB, bool F8OUT>
__global__ __launch_bounds__(256) void gemm_lds(const f16* __restrict__ A,
                                                const f16* __restrict__ BT,
                                                u8* __restrict__ C8,
                                                f16* __restrict__ C16,
                                                int M, int Nout) {
  __shared__ f16 As[128 * 130];
  __shared__ f16 Bs[128 * 130];
  const int nx = (M + 127) / 128;
  const int chunk = nx * YB / 8;
  const int bid = blockIdx.x;
  const int p = (bid % 8) * chunk + bid / 8;  // XCD swizzle (nx*YB % 8 == 0)
  const int bx = p / YB, by = p % YB;
  const int rowblk = bx * 128, colblk = by * 128;

  const int t = threadIdx.x;
  const int sr = t >> 4;
  const int sc = (t & 15) * 8;  // 16B chunks
#pragma unroll
  for (int pp = 0; pp < 8; pp++) {
    int r = pp * 16 + sr;
    int gr = rowblk + r;
    gr = gr < M ? gr : M - 1;
    *(uint4*)&As[r * 130 + sc] = *(const uint4*)(A + (size_t)gr * 128 + sc);
    *(uint4*)&Bs[r * 130 + sc] = *(const uint4*)(BT + (size_t)(colblk + r) * 128 + sc);
  }
  __syncthreads();

  const int lane = t & 63, w = t >> 6;
  const int wm = w >> 1, wn = w & 1;
  const int lr = lane & 15, lk = (lane >> 4) * 8;
  const f16* Af = &As[(wm * 64 + lr) * 130 + lk];
  const f16* Bf = &Bs[(wn * 64 + lr) * 130 + lk];

  f32x4 acc[4][4] = {};
#pragma unroll
  for (int ks = 0; ks < 4; ks++) {
    f16x8 a[4], b[4];
#pragma unroll
    for (int m = 0; m < 4; m++) a[m] = *(const f16x8*)(Af + m * 16 * 130 + ks * 32);
#pragma unroll
    for (int n = 0; n < 4; n++) b[n] = *(const f16x8*)(Bf + n * 16 * 130 + ks * 32);
#pragma unroll
    for (int m = 0; m < 4; m++)
#pragma unroll
      for (int n = 0; n < 4; n++)
        acc[m][n] = __builtin_amdgcn_mfma_f32_16x16x32_f16(a[m], b[n], acc[m][n], 0, 0, 0);
  }
  __syncthreads();  // all As reads done before ct aliases it

  f16* ct = As;  // reuse as [64][136] (17.4 KB <= 33.3 KB)
#pragma unroll
  for (int half = 0; half < 2; half++) {
    if (wm == half) {
#pragma unroll
      for (int m = 0; m < 4; m++) {
        int rbase = m * 16 + (lane >> 4) * 4;
#pragma unroll
        for (int r = 0; r < 4; r++)
#pragma unroll
          for (int n = 0; n < 4; n++)
            ct[(rbase + r) * 136 + wn * 64 + n * 16 + lr] = (f16)acc[m][n][r];
      }
    }
    __syncthreads();
#pragma unroll
    for (int rr = (t >> 4); rr < 64; rr += 16) {
      int gr = rowblk + half * 64 + rr;
      if (gr < M) {
        int cidx = (t & 15) * 8;
        f16x8 v = *(const f16x8*)(&ct[rr * 136 + cidx]);
        if (F8OUT) {
          int lo = __builtin_amdgcn_cvt_pk_fp8_f32((float)v[0], (float)v[1], 0, false);
          lo = __builtin_amdgcn_cvt_pk_fp8_f32((float)v[2], (float)v[3], lo, true);
          int hi = __builtin_amdgcn_cvt_pk_fp8_f32((float)v[4], (float)v[5], 0, false);
          hi = __builtin_amdgcn_cvt_pk_fp8_f32((float)v[6], (float)v[7], hi, true);
          uint2 o;
          o.x = (uint32)lo;
          o.y = (uint32)hi;
          *(uint2*)(C8 + (size_t)gr * 2048 + colblk + cidx) = o;
        } else {
          *(uint4*)(C16 + (size_t)gr * Nout + colblk + cidx) =
              __builtin_bit_cast(uint4, v);
        }
      }
    }
    __syncthreads();
  }
}

// ---------------- fused GATv2 aggregation ----------------
// NOTE (R14): persistent grid-stride agg REGRESSED; keep 1-shot blocks.
// NOTE (R11): 8-deep masked merge REGRESSED; keep 4-deep + scalar tail.
struct LV { f16x2 v[4]; };

__device__ __forceinline__ f16x2 bc2(uint32 x) { return __builtin_bit_cast(f16x2, x); }

__device__ __forceinline__ LV load8(const char* __restrict__ base, uint32 off) {
  uint4 r = *(const uint4*)(base + off);
  LV o;
  o.v[0] = bc2(r.x); o.v[1] = bc2(r.y); o.v[2] = bc2(r.z); o.v[3] = bc2(r.w);
  return o;
}

// fp8-e4m3 gather: 8 bytes -> 8 f16 via HW cvt (exact embeddings).
__device__ __forceinline__ LV load8_f8(const char* __restrict__ base, uint32 off) {
  uint2 w = *(const uint2*)(base + off);
  auto a = __builtin_amdgcn_cvt_pk_f32_fp8((int)w.x, false);
  auto b = __builtin_amdgcn_cvt_pk_f32_fp8((int)w.x, true);
  auto c = __builtin_amdgcn_cvt_pk_f32_fp8((int)w.y, false);
  auto d = __builtin_amdgcn_cvt_pk_f32_fp8((int)w.y, true);
  LV o;
  o.v[0] = __builtin_bit_cast(f16x2, __builtin_amdgcn_cvt_pkrtz(a[0], a[1]));
  o.v[1] = __builtin_bit_cast(f16x2, __builtin_amdgcn_cvt_pkrtz(b[0], b[1]));
  o.v[2] = __builtin_bit_cast(f16x2, __builtin_amdgcn_cvt_pkrtz(c[0], c[1]));
  o.v[3] = __builtin_bit_cast(f16x2, __builtin_amdgcn_cvt_pkrtz(d[0], d[1]));
  return o;
}

template <bool F8>
__device__ __forceinline__ LV loadxl(const char* __restrict__ p, uint32 off) {
  if constexpr (F8) return load8_f8(p, off);
  else return load8(p, off);
}

__device__ __forceinline__ f16x2 leaky2(f16x2 z) {
  f16x2 zs = z * (f16)0.2f;
  return __builtin_elementwise_max(z, zs);
}

__device__ __forceinline__ float edot(const LV& x, const f16x2* xr2, const f16x2* att2) {
  float ea = 0.f, eb = 0.f;
  ea = __builtin_amdgcn_fdot2(leaky2(x.v[0] + xr2[0]), att2[0], ea, false);
  eb = __builtin_amdgcn_fdot2(leaky2(x.v[1] + xr2[1]), att2[1], eb, false);
  ea = __builtin_amdgcn_fdot2(leaky2(x.v[2] + xr2[2]), att2[2], ea, false);
  eb = __builtin_amdgcn_fdot2(leaky2(x.v[3] + xr2[3]), att2[3], eb, false);
  return ea + eb;
}

template <int PAT>
__device__ __forceinline__ float swz(float x) {
  return __int_as_float(__builtin_amdgcn_ds_swizzle(__float_as_int(x), PAT));
}

__device__ __forceinline__ void red16x4(float& a, float& b, float& c, float& d) {
  a += swz<0x041F>(a); b += swz<0x041F>(b); c += swz<0x041F>(c); d += swz<0x041F>(d);
  a += swz<0x081F>(a); b += swz<0x081F>(b); c += swz<0x081F>(c); d += swz<0x081F>(d);
  a += swz<0x101F>(a); b += swz<0x101F>(b); c += swz<0x101F>(c); d += swz<0x101F>(d);
  a += swz<0x201F>(a); b += swz<0x201F>(b); c += swz<0x201F>(c); d += swz<0x201F>(d);
}
__device__ __forceinline__ float red16(float a) {
  a += swz<0x041F>(a);
  a += swz<0x081F>(a);
  a += swz<0x101F>(a);
  a += swz<0x201F>(a);
  return a;
}

// H heads; DG dst-groups/block; F8: xl fp8; XR8: xr fp8; LGXL/LGXR log2 strides.
template <int H, int DG, bool RELU, bool WF32, bool F8, bool XR8, int LGXL, int LGXR>
__global__ __launch_bounds__(H * DG * 64) void agg_kernel(
    const f16* __restrict__ h_in, const char* __restrict__ xlp,
    const char* __restrict__ xrp, const float* __restrict__ att,
    const float* __restrict__ bias, const int* __restrict__ csr,
    const int* __restrict__ rowstart, const int* __restrict__ perm,
    float* __restrict__ h_out, f16* __restrict__ hh) {
  __shared__ float headout[H][4 * DG][DH];
  __shared__ int nodes[4 * DG];
  const int wv = threadIdx.x >> 6;
  const int h = wv & (H - 1);
  const int dg = wv / H;
  const int lane = threadIdx.x & 63;
  const int g = lane >> 4, u = lane & 15;
  const int c0 = u * 8;
  if (threadIdx.x < 4 * DG) nodes[threadIdx.x] = perm[blockIdx.x * 4 * DG + threadIdx.x];
  const int dst = perm[blockIdx.x * 4 * DG + dg * 4 + g];
  const uint32 loff_xl = (uint32)(h * DH + c0) << (F8 ? 0 : 1);
  const uint32 loff_xr = (uint32)(h * DH + c0) << (XR8 ? 0 : 1);

  f16x2 att2[4], xr2[4];
  {
    const float* ap = att + h * DH + c0;
    float a0[8];
    *(float4*)a0 = *(const float4*)ap;
    *(float4*)(a0 + 4) = *(const float4*)(ap + 4);
#pragma unroll
    for (int q = 0; q < 4; q++) att2[q] = f16x2{(f16)a0[2 * q], (f16)a0[2 * q + 1]};
    LV xrv = loadxl<XR8>(xrp, ((uint32)dst << LGXR) + loff_xr);
#pragma unroll
    for (int q = 0; q < 4; q++) xr2[q] = xrv.v[q];
  }

  const int js = rowstart[dst], je = rowstart[dst + 1];

  // self loop seed
  float m, s;
  f16x2 acc[4];
  {
    LV xv = loadxl<F8>(xlp, ((uint32)dst << LGXL) + loff_xl);
    m = red16(edot(xv, xr2, att2));
    s = 1.f;
#pragma unroll
    for (int q = 0; q < 4; q++) acc[q] = xv.v[q];
  }

  // 4-deep prefetch over CSR row (indices clamped to je-1)
  LV pf0, pf1, pf2, pf3;
  {
    int ja = js < je ? js : je - 1;
    int jb = js + 1 < je ? js + 1 : je - 1;
    int jc = js + 2 < je ? js + 2 : je - 1;
    int jd = js + 3 < je ? js + 3 : je - 1;
    if (js < je) {
      pf0 = loadxl<F8>(xlp, ((uint32)csr[ja] << LGXL) + loff_xl);
      pf1 = loadxl<F8>(xlp, ((uint32)csr[jb] << LGXL) + loff_xl);
      pf2 = loadxl<F8>(xlp, ((uint32)csr[jc] << LGXL) + loff_xl);
      pf3 = loadxl<F8>(xlp, ((uint32)csr[jd] << LGXL) + loff_xl);
    }
  }

  int j = js;
  for (; j + 3 < je; j += 4) {
    LV cv0 = pf0, cv1 = pf1, cv2 = pf2, cv3 = pf3;
    int ja = j + 4 < je ? j + 4 : je - 1;
    int jb = j + 5 < je ? j + 5 : je - 1;
    int jc = j + 6 < je ? j + 6 : je - 1;
    int jd = j + 7 < je ? j + 7 : je - 1;
    pf0 = loadxl<F8>(xlp, ((uint32)csr[ja] << LGXL) + loff_xl);
    pf1 = loadxl<F8>(xlp, ((uint32)csr[jb] << LGXL) + loff_xl);
    pf2 = loadxl<F8>(xlp, ((uint32)csr[jc] << LGXL) + loff_xl);
    pf3 = loadxl<F8>(xlp, ((uint32)csr[jd] << LGXL) + loff_xl);

    float e0 = edot(cv0, xr2, att2);
    float e1 = edot(cv1, xr2, att2);
    float e2 = edot(cv2, xr2, att2);
    float e3 = edot(cv3, xr2, att2);
    red16x4(e0, e1, e2, e3);

    float mn = fmaxf(fmaxf(fmaxf(m, e0), fmaxf(e1, e2)), e3);
    float a = __expf(m - mn);
    float p0 = __expf(e0 - mn);
    float p1 = __expf(e1 - mn);
    float p2 = __expf(e2 - mn);
    float p3 = __expf(e3 - mn);
    s = s * a + ((p0 + p1) + (p2 + p3));
    f16 ah = (f16)a, g0 = (f16)p0, g1 = (f16)p1, g2 = (f16)p2, g3 = (f16)p3;
    f16x2 a2 = {ah, ah}, q0 = {g0, g0}, q1 = {g1, g1}, q2 = {g2, g2}, q3 = {g3, g3};
#pragma unroll
    for (int q = 0; q < 4; q++) {
      f16x2 t = acc[q] * a2;
      t = cv0.v[q] * q0 + t;
      t = cv1.v[q] * q1 + t;
      t = cv2.v[q] * q2 + t;
      t = cv3.v[q] * q3 + t;
      acc[q] = t;
    }
    m = mn;
  }
  // tail: consume remaining prefetched edges one at a time
  for (int t = 0; j < je; j++, t++) {
    LV cv = (t == 0) ? pf0 : (t == 1) ? pf1 : pf2;
    float e = red16(edot(cv, xr2, att2));
    float mn = fmaxf(m, e);
    float a = __expf(m - mn);
    float p = __expf(e - mn);
    s = s * a + p;
    f16 ah = (f16)a, gh = (f16)p;
    f16x2 a2 = {ah, ah}, p2 = {gh, gh};
#pragma unroll
    for (int q = 0; q < 4; q++) acc[q] = acc[q] * a2 + cv.v[q] * p2;
    m = mn;
  }

  float inv = 1.f / s;
#pragma unroll
  for (int q = 0; q < 4; q++) {
    headout[h][dg * 4 + g][c0 + 2 * q] = (float)acc[q][0] * inv;
    headout[h][dg * 4 + g][c0 + 2 * q + 1] = (float)acc[q][1] * inv;
  }
  __syncthreads();
  for (int t = threadIdx.x; t < 4 * DG * DH; t += H * DG * 64) {
    int d = t >> 7, c = t & 127;
    float sum = 0.f;
#pragma unroll
    for (int q = 0; q < H; q++) sum += headout[q][d][c];
    float r = sum * (1.f / H) + bias[c];
    if (RELU) r = fmaxf(r, 0.f);
    int node = nodes[d];
    float o = r + (float)h_in[(size_t)node * DH + c];
    if (WF32) h_out[(size_t)node * DH + c] = o;
    else hh[(size_t)node * DH + c] = (f16)o;
  }
}

extern "C" void kernel_launch(void* const* d_in, const int* in_sizes, int n_in,
                              void* d_out, int out_size, void* d_ws, size_t ws_size,
                              hipStream_t stream) {
  const float* x = (const float*)d_in[0];
  const int* ei = (const int*)d_in[1];
  const float* Wl1 = (const float*)d_in[2];
  const float* Wr1 = (const float*)d_in[3];
  const float* att1 = (const float*)d_in[4];
  const float* b1 = (const float*)d_in[5];
  const float* Wl2 = (const float*)d_in[6];
  const float* Wr2 = (const float*)d_in[7];
  const float* att2 = (const float*)d_in[8];
  const float* b2 = (const float*)d_in[9];
  const float* Wl3 = (const float*)d_in[10];
  const float* Wr3 = (const float*)d_in[11];
  const float* att3 = (const float*)d_in[12];
  const float* b3 = (const float*)d_in[13];
  float* out = (float*)d_out;

  char* p = (char*)d_ws;
  f16* xlr = (f16*)p; p += (size_t)NN * 2048 * 2;   // layer-3 f16 buffer
  u8* xl8  = (u8*)p;  p += (size_t)NN * 2048;       // layers 1-2 fp8 buffer (xl|xr)
  f16* xh  = (f16*)p; p += (size_t)NN * DH * 2;
  f16* h1h = (f16*)p; p += (size_t)NN * DH * 2;
  f16* h2h = (f16*)p; p += (size_t)NN * DH * 2;
  f16* WT1 = (f16*)p; p += (size_t)2048 * 128 * 2;
  f16* WT2 = (f16*)p; p += (size_t)2048 * 128 * 2;
  f16* WT3 = (f16*)p; p += (size_t)1024 * 128 * 2;
  int* deg      = (int*)p; p += (size_t)NN * 4;
  int* cursor   = (int*)p; p += (size_t)NN * 4;
  int* rowstart = (int*)p; p += (size_t)(NN + 1) * 4;
  int* perm     = (int*)p; p += (size_t)NN * 4;
  int* bsum     = (int*)p; p += (size_t)32 * 4;
  int* ghist    = (int*)p; p += (size_t)20 * 64 * 4;
  int* csr      = (int*)p;

  const int* esrc = ei;
  const int* edst = ei + NE;

  const int nbc = (NN + 1023) / 1024;  // 20 CSR-build blocks

  hipMemsetAsync(deg, 0, sizeof(int) * 2 * NN, stream);  // deg + cursor
  conv_count_kernel<<<(NN * DH / 4 + 255) / 256, 256, 0, stream>>>(
      x, xh, NN * DH / 4, edst, deg, NE);
  csr_p1<<<nbc, 1024, 0, stream>>>(deg, rowstart, bsum, ghist, NN);
  csr_p3<<<nbc, 1024, 0, stream>>>(deg, rowstart, bsum, ghist, perm, NN, nbc);
  scatter_kernel<<<(NE + 255) / 256, 256, 0, stream>>>(esrc, edst, rowstart, cursor, csr, NE);
  sort_kernel<<<(NN * 16 + 255) / 256, 256, 0, stream>>>(rowstart, csr, perm, NN);
  transconv_all<<<dim3(32, 4, 6), 256, 0, stream>>>(
      Wl1, Wr1, Wl2, Wr2, Wl3, Wr3,
      WT1, WT1 + (size_t)1024 * 128, WT2, WT2 + (size_t)1024 * 128,
      WT3, WT3 + (size_t)512 * 128);

  const int nx = (NN + 127) / 128;  // 157

  // layer 1: C fully fp8 (xl cols 0-1023, xr cols 1024-2047; 2048 B rows)
  gemm_lds<16, true><<<nx * 16, 256, 0, stream>>>(xh, WT1, xl8, nullptr, NN, 2048);
  agg_kernel<8, 1, true, false, true, true, 11, 11><<<NN / 4, 512, 0, stream>>>(
      xh, (const char*)xl8, (const char*)xl8 + 1024, att1, b1, csr, rowstart,
      perm, nullptr, h1h);
  // layer 2: same scheme
  gemm_lds<16, true><<<nx * 16, 256, 0, stream>>>(h1h, WT2, xl8, nullptr, NN, 2048);
  agg_kernel<8, 1, true, false, true, true, 11, 11><<<NN / 4, 512, 0, stream>>>(
      h1h, (const char*)xl8, (const char*)xl8 + 1024, att2, b2, csr, rowstart,
      perm, nullptr, h2h);
  // layer 3: f16 (stride 2048 B; xr at +1024 B), output f32 + residual
  gemm_lds<8, false><<<nx * 8, 256, 0, stream>>>(h2h, WT3, nullptr, xlr, NN, 1024);
  agg_kernel<4, 2, false, true, false, false, 11, 11><<<NN / 8, 512, 0, stream>>>(
      h2h, (const char*)xlr, (const char*)xlr + 1024, att3, b3, csr, rowstart,
      perm, out, nullptr);
}

// Round 21
// 286.918 us; speedup vs baseline: 1.1701x; 1.1315x over previous
//
#include <hip/hip_runtime.h>
#include <math.h>

#define NN 20000
#define NE 160000
#define DH 128

typedef _Float16 f16;
typedef f16 f16x2 __attribute__((ext_vector_type(2)));
typedef f16 f16x4 __attribute__((ext_vector_type(4)));
typedef f16 f16x8 __attribute__((ext_vector_type(8)));
typedef float f32x4 __attribute__((ext_vector_type(4)));
typedef unsigned int uint32;
typedef unsigned char u8;

// ---------------- prep: fused x->f16 convert + degree count ----------------
__global__ void conv_count_kernel(const float* __restrict__ X, f16* __restrict__ XH,
                                  int n4, const int* __restrict__ edst,
                                  int* __restrict__ deg, int ne) {
  int i = blockIdx.x * blockDim.x + threadIdx.x;
  if (i < n4) {
    float4 v = *(const float4*)(X + (size_t)i * 4);
    f16x4 o = {(f16)v.x, (f16)v.y, (f16)v.z, (f16)v.w};
    *(f16x4*)(XH + (size_t)i * 4) = o;
  }
  if (i < ne) atomicAdd(&deg[edst[i]], 1);
}

// ---------------- CSR build (2-phase) ----------------
__global__ __launch_bounds__(1024) void csr_p1(const int* __restrict__ deg,
                                               int* __restrict__ rowstart,
                                               int* __restrict__ bsum,
                                               int* __restrict__ ghist, int n) {
  __shared__ int wsum[16];
  __shared__ int lhist[64];
  const int tid = threadIdx.x;
  const int lane = tid & 63, w = tid >> 6;
  if (tid < 64) lhist[tid] = 0;
  __syncthreads();
  int i = blockIdx.x * 1024 + tid;
  int d = (i < n) ? deg[i] : 0;
  if (i < n) atomicAdd(&lhist[d < 63 ? d : 63], 1);
  int v = d;
#pragma unroll
  for (int off = 1; off < 64; off <<= 1) {
    int u = __shfl_up(v, off, 64);
    if (lane >= off) v += u;
  }
  if (lane == 63) wsum[w] = v;
  __syncthreads();
  if (w == 0) {
    int t = (lane < 16) ? wsum[lane] : 0;
#pragma unroll
    for (int off = 1; off < 16; off <<= 1) {
      int u = __shfl_up(t, off, 64);
      if (lane >= off) t += u;
    }
    if (lane < 16) wsum[lane] = t;
  }
  __syncthreads();
  int add = (w > 0 ? wsum[w - 1] : 0);
  if (i < n) rowstart[i + 1] = v + add;
  if (tid == 0) bsum[blockIdx.x] = wsum[15];
  if (tid < 64) ghist[blockIdx.x * 64 + tid] = lhist[tid];
}

__global__ __launch_bounds__(1024) void csr_p3(const int* __restrict__ deg,
                                               int* __restrict__ rowstart,
                                               const int* __restrict__ bsum,
                                               const int* __restrict__ ghist,
                                               int* __restrict__ perm, int n, int nb) {
  __shared__ int lcur[64];
  __shared__ int base[64];
  __shared__ int radd_s;
  const int tid = threadIdx.x;
  if (tid < 64) {
    lcur[tid] = 0;
    int pre = 0, tot = 0;
    for (int b = 0; b < nb; b++) {
      int v = ghist[b * 64 + tid];
      pre += (b < (int)blockIdx.x) ? v : 0;
      tot += v;
    }
    int incl = tot;
#pragma unroll
    for (int off = 1; off < 64; off <<= 1) {
      int u = __shfl_up(incl, off, 64);
      if (tid >= off) incl += u;
    }
    base[tid] = (n - incl) + pre;  // descending bucket start + within-bin prefix
  }
  if (tid == 0) {
    int r = 0;
    for (int b = 0; b < (int)blockIdx.x; b++) r += bsum[b];
    radd_s = r;
  }
  __syncthreads();
  int i = blockIdx.x * 1024 + tid;
  if (i < n) {
    rowstart[i + 1] += radd_s;
    int d = deg[i];
    int b = d < 63 ? d : 63;
    int pos = atomicAdd(&lcur[b], 1);
    perm[base[b] + pos] = i;
  }
  if (blockIdx.x == 0 && tid == 0) rowstart[0] = 0;
}

__global__ void scatter_kernel(const int* __restrict__ src, const int* __restrict__ dstp,
                               const int* __restrict__ rowstart, int* __restrict__ cursor,
                               int* __restrict__ csr, int n) {
  int i = blockIdx.x * blockDim.x + threadIdx.x;
  if (i < n) {
    int d = dstp[i];
    int pos = atomicAdd(&cursor[d], 1);
    csr[rowstart[d] + pos] = src[i];
  }
}

// one 16-lane subgroup per row; 16-element bitonic network.
__global__ void sort_kernel(const int* __restrict__ rowstart, int* __restrict__ csr,
                            const int* __restrict__ perm, int n) {
  int idx = blockIdx.x * blockDim.x + threadIdx.x;
  int sub = idx >> 4;
  int u = idx & 15;
  if (sub >= n) return;
  int i = perm[sub];
  int a = rowstart[i], b = rowstart[i + 1];
  int d = b - a;
  if (d <= 1) return;
  if (d <= 16) {
    int v = (u < d) ? csr[a + u] : 0x7FFFFFFF;
#pragma unroll
    for (int k = 2; k <= 16; k <<= 1) {
#pragma unroll
      for (int j = 16; j > 0; j >>= 1) {
        if (j > (k >> 1)) continue;
        int o = __shfl_xor(v, j, 64);
        bool takeMin = (((u & k) == 0) == ((u & j) == 0));
        v = takeMin ? (v < o ? v : o) : (v > o ? v : o);
      }
    }
    if (u < d) csr[a + u] = v;
  } else if (u == 0) {
    for (int j = a + 1; j < b; j++) {
      int v = csr[j];
      int k = j - 1;
      while (k >= a && csr[k] > v) { csr[k + 1] = csr[k]; k--; }
      csr[k + 1] = v;
    }
  }
}

// ---------------- weights: W [128][HC] f32 -> WT [HC][128] f16 ----------------
__global__ __launch_bounds__(256) void transconv_all(
    const float* __restrict__ W0, const float* __restrict__ W1,
    const float* __restrict__ W2, const float* __restrict__ W3,
    const float* __restrict__ W4, const float* __restrict__ W5,
    f16* O0, f16* O1, f16* O2, f16* O3, f16* O4, f16* O5) {
  const float* W; f16* O; int HC;
  switch (blockIdx.z) {
    case 0: W = W0; O = O0; HC = 1024; break;
    case 1: W = W1; O = O1; HC = 1024; break;
    case 2: W = W2; O = O2; HC = 1024; break;
    case 3: W = W3; O = O3; HC = 1024; break;
    case 4: W = W4; O = O4; HC = 512; break;
    default: W = W5; O = O5; HC = 512; break;
  }
  int c0 = blockIdx.x * 32;
  if (c0 >= HC) return;
  __shared__ float t[32][33];
  int k0 = blockIdx.y * 32;
  int tx = threadIdx.x & 31, ty = threadIdx.x >> 5;  // 32 x 8
#pragma unroll
  for (int j = 0; j < 4; j++) {
    int k = k0 + ty + j * 8;
    t[ty + j * 8][tx] = W[(size_t)k * HC + c0 + tx];
  }
  __syncthreads();
#pragma unroll
  for (int j = 0; j < 4; j++) {
    int c = c0 + ty + j * 8;
    O[(size_t)c * 128 + k0 + tx] = (f16)t[tx][ty + j * 8];
  }
}

// ---------------- f16 MFMA GEMM, whole-row fp8 output (R17 structure) -------
// R18-R20 lessons: one-pass 128x128 fragment-direct (this shape) = 46.6us;
// two-pass epilogue = same; 64x32 retile = 61.9 (worse); LDS-staged = 56.5
// (worse). This is the best measured variant; GEMM floor unexplained but
// consistent. Do not re-tile without new counter evidence.
// Output: all YB*128 cols as fp8-e4m3, row stride = YB*128 bytes.
template <int YB>
__global__ __launch_bounds__(256) void gemm_f8(const f16* __restrict__ A,
                                               const f16* __restrict__ BT,
                                               u8* __restrict__ C8, int M) {
  const int ROWB = YB * 128;
  const int nx = (M + 127) / 128;
  const int chunk = nx * YB / 8;
  const int bid = blockIdx.x;
  const int p = (bid % 8) * chunk + bid / 8;
  const int bx = p / YB, by = p % YB;

  const int w = threadIdx.x >> 6, lane = threadIdx.x & 63;
  const int wm = w >> 1, wn = w & 1;
  const int row0 = bx * 128 + wm * 64;
  const int col0 = by * 128 + wn * 64;
  const int lr = lane & 15, lk = (lane >> 4) * 8;

  __shared__ f16 ct[128][144];

  f32x4 acc[4][4] = {};
  const f16* Arow[4];
  const f16* Brow[4];
#pragma unroll
  for (int m = 0; m < 4; m++) {
    int r = row0 + m * 16 + lr;
    r = r < M ? r : M - 1;
    Arow[m] = A + (size_t)r * 128 + lk;
  }
#pragma unroll
  for (int n = 0; n < 4; n++) {
    int c = col0 + n * 16 + lr;
    Brow[n] = BT + (size_t)c * 128 + lk;
  }
#pragma unroll
  for (int ks = 0; ks < 4; ks++) {
    f16x8 a[4], b[4];
#pragma unroll
    for (int m = 0; m < 4; m++) a[m] = *(const f16x8*)(Arow[m] + ks * 32);
#pragma unroll
    for (int n = 0; n < 4; n++) b[n] = *(const f16x8*)(Brow[n] + ks * 32);
#pragma unroll
    for (int m = 0; m < 4; m++)
#pragma unroll
      for (int n = 0; n < 4; n++)
        acc[m][n] = __builtin_amdgcn_mfma_f32_16x16x32_f16(a[m], b[n], acc[m][n], 0, 0, 0);
  }
  const int lrow = wm * 64, lcol = wn * 64;
#pragma unroll
  for (int m = 0; m < 4; m++) {
    int rbase = lrow + m * 16 + (lane >> 4) * 4;
#pragma unroll
    for (int r = 0; r < 4; r++) {
#pragma unroll
      for (int n = 0; n < 4; n++) {
        ct[rbase + r][lcol + n * 16 + lr] = (f16)acc[m][n][r];
      }
    }
  }
  __syncthreads();
  const int t = threadIdx.x;
  const int cidx = (t & 15) * 8;
  const int rowblk = bx * 128, colblk = by * 128;
#pragma unroll
  for (int rr = (t >> 4); rr < 128; rr += 16) {
    int gr = rowblk + rr;
    if (gr < M) {
      f16x8 v = *(const f16x8*)(&ct[rr][cidx]);
      int lo = __builtin_amdgcn_cvt_pk_fp8_f32((float)v[0], (float)v[1], 0, false);
      lo = __builtin_amdgcn_cvt_pk_fp8_f32((float)v[2], (float)v[3], lo, true);
      int hi = __builtin_amdgcn_cvt_pk_fp8_f32((float)v[4], (float)v[5], 0, false);
      hi = __builtin_amdgcn_cvt_pk_fp8_f32((float)v[6], (float)v[7], hi, true);
      uint2 o;
      o.x = (uint32)lo;
      o.y = (uint32)hi;
      *(uint2*)(C8 + (size_t)gr * ROWB + colblk + cidx) = o;
    }
  }
}

// ---------------- fused GATv2 aggregation ----------------
// NOTE (R14): persistent grid-stride agg REGRESSED; keep 1-shot blocks.
// NOTE (R11): 8-deep masked merge REGRESSED; keep 4-deep + scalar tail.
struct LV { f16x2 v[4]; };

__device__ __forceinline__ f16x2 bc2(uint32 x) { return __builtin_bit_cast(f16x2, x); }

// fp8-e4m3 gather: 8 bytes -> 8 f16 via HW cvt (exact embeddings).
__device__ __forceinline__ LV load8_f8(const char* __restrict__ base, uint32 off) {
  uint2 w = *(const uint2*)(base + off);
  auto a = __builtin_amdgcn_cvt_pk_f32_fp8((int)w.x, false);
  auto b = __builtin_amdgcn_cvt_pk_f32_fp8((int)w.x, true);
  auto c = __builtin_amdgcn_cvt_pk_f32_fp8((int)w.y, false);
  auto d = __builtin_amdgcn_cvt_pk_f32_fp8((int)w.y, true);
  LV o;
  o.v[0] = __builtin_bit_cast(f16x2, __builtin_amdgcn_cvt_pkrtz(a[0], a[1]));
  o.v[1] = __builtin_bit_cast(f16x2, __builtin_amdgcn_cvt_pkrtz(b[0], b[1]));
  o.v[2] = __builtin_bit_cast(f16x2, __builtin_amdgcn_cvt_pkrtz(c[0], c[1]));
  o.v[3] = __builtin_bit_cast(f16x2, __builtin_amdgcn_cvt_pkrtz(d[0], d[1]));
  return o;
}

__device__ __forceinline__ f16x2 leaky2(f16x2 z) {
  f16x2 zs = z * (f16)0.2f;
  return __builtin_elementwise_max(z, zs);
}

__device__ __forceinline__ float edot(const LV& x, const f16x2* xr2, const f16x2* att2) {
  float ea = 0.f, eb = 0.f;
  ea = __builtin_amdgcn_fdot2(leaky2(x.v[0] + xr2[0]), att2[0], ea, false);
  eb = __builtin_amdgcn_fdot2(leaky2(x.v[1] + xr2[1]), att2[1], eb, false);
  ea = __builtin_amdgcn_fdot2(leaky2(x.v[2] + xr2[2]), att2[2], ea, false);
  eb = __builtin_amdgcn_fdot2(leaky2(x.v[3] + xr2[3]), att2[3], eb, false);
  return ea + eb;
}

template <int PAT>
__device__ __forceinline__ float swz(float x) {
  return __int_as_float(__builtin_amdgcn_ds_swizzle(__float_as_int(x), PAT));
}

__device__ __forceinline__ void red16x4(float& a, float& b, float& c, float& d) {
  a += swz<0x041F>(a); b += swz<0x041F>(b); c += swz<0x041F>(c); d += swz<0x041F>(d);
  a += swz<0x081F>(a); b += swz<0x081F>(b); c += swz<0x081F>(c); d += swz<0x081F>(d);
  a += swz<0x101F>(a); b += swz<0x101F>(b); c += swz<0x101F>(c); d += swz<0x101F>(d);
  a += swz<0x201F>(a); b += swz<0x201F>(b); c += swz<0x201F>(c); d += swz<0x201F>(d);
}
__device__ __forceinline__ float red16(float a) {
  a += swz<0x041F>(a);
  a += swz<0x081F>(a);
  a += swz<0x101F>(a);
  a += swz<0x201F>(a);
  return a;
}

// H heads; DG dst-groups/block; LGROW: log2 fp8 row stride; XROFF: xr byte off.
template <int H, int DG, bool RELU, bool WF32, int LGROW, int XROFF>
__global__ __launch_bounds__(H * DG * 64) void agg_kernel(
    const f16* __restrict__ h_in, const char* __restrict__ xp,
    const float* __restrict__ att, const float* __restrict__ bias,
    const int* __restrict__ csr, const int* __restrict__ rowstart,
    const int* __restrict__ perm,
    float* __restrict__ h_out, f16* __restrict__ hh) {
  __shared__ float headout[H][4 * DG][DH];
  __shared__ int nodes[4 * DG];
  const int wv = threadIdx.x >> 6;
  const int h = wv & (H - 1);
  const int dg = wv / H;
  const int lane = threadIdx.x & 63;
  const int g = lane >> 4, u = lane & 15;
  const int c0 = u * 8;
  if (threadIdx.x < 4 * DG) nodes[threadIdx.x] = perm[blockIdx.x * 4 * DG + threadIdx.x];
  const int dst = perm[blockIdx.x * 4 * DG + dg * 4 + g];
  const uint32 loff = (uint32)(h * DH + c0);  // fp8: 1 byte/elem

  f16x2 att2[4], xr2[4];
  {
    const float* ap = att + h * DH + c0;
    float a0[8];
    *(float4*)a0 = *(const float4*)ap;
    *(float4*)(a0 + 4) = *(const float4*)(ap + 4);
#pragma unroll
    for (int q = 0; q < 4; q++) att2[q] = f16x2{(f16)a0[2 * q], (f16)a0[2 * q + 1]};
    LV xrv = load8_f8(xp, ((uint32)dst << LGROW) + XROFF + loff);
#pragma unroll
    for (int q = 0; q < 4; q++) xr2[q] = xrv.v[q];
  }

  const int js = rowstart[dst], je = rowstart[dst + 1];

  // self loop seed
  float m, s;
  f16x2 acc[4];
  {
    LV xv = load8_f8(xp, ((uint32)dst << LGROW) + loff);
    m = red16(edot(xv, xr2, att2));
    s = 1.f;
#pragma unroll
    for (int q = 0; q < 4; q++) acc[q] = xv.v[q];
  }

  // 4-deep prefetch over CSR row (indices clamped to je-1)
  LV pf0, pf1, pf2, pf3;
  {
    int ja = js < je ? js : je - 1;
    int jb = js + 1 < je ? js + 1 : je - 1;
    int jc = js + 2 < je ? js + 2 : je - 1;
    int jd = js + 3 < je ? js + 3 : je - 1;
    if (js < je) {
      pf0 = load8_f8(xp, ((uint32)csr[ja] << LGROW) + loff);
      pf1 = load8_f8(xp, ((uint32)csr[jb] << LGROW) + loff);
      pf2 = load8_f8(xp, ((uint32)csr[jc] << LGROW) + loff);
      pf3 = load8_f8(xp, ((uint32)csr[jd] << LGROW) + loff);
    }
  }

  int j = js;
  for (; j + 3 < je; j += 4) {
    LV cv0 = pf0, cv1 = pf1, cv2 = pf2, cv3 = pf3;
    int ja = j + 4 < je ? j + 4 : je - 1;
    int jb = j + 5 < je ? j + 5 : je - 1;
    int jc = j + 6 < je ? j + 6 : je - 1;
    int jd = j + 7 < je ? j + 7 : je - 1;
    pf0 = load8_f8(xp, ((uint32)csr[ja] << LGROW) + loff);
    pf1 = load8_f8(xp, ((uint32)csr[jb] << LGROW) + loff);
    pf2 = load8_f8(xp, ((uint32)csr[jc] << LGROW) + loff);
    pf3 = load8_f8(xp, ((uint32)csr[jd] << LGROW) + loff);

    float e0 = edot(cv0, xr2, att2);
    float e1 = edot(cv1, xr2, att2);
    float e2 = edot(cv2, xr2, att2);
    float e3 = edot(cv3, xr2, att2);
    red16x4(e0, e1, e2, e3);

    float mn = fmaxf(fmaxf(fmaxf(m, e0), fmaxf(e1, e2)), e3);
    float a = __expf(m - mn);
    float p0 = __expf(e0 - mn);
    float p1 = __expf(e1 - mn);
    float p2 = __expf(e2 - mn);
    float p3 = __expf(e3 - mn);
    s = s * a + ((p0 + p1) + (p2 + p3));
    f16 ah = (f16)a, g0 = (f16)p0, g1 = (f16)p1, g2 = (f16)p2, g3 = (f16)p3;
    f16x2 a2 = {ah, ah}, q0 = {g0, g0}, q1 = {g1, g1}, q2 = {g2, g2}, q3 = {g3, g3};
#pragma unroll
    for (int q = 0; q < 4; q++) {
      f16x2 t = acc[q] * a2;
      t = cv0.v[q] * q0 + t;
      t = cv1.v[q] * q1 + t;
      t = cv2.v[q] * q2 + t;
      t = cv3.v[q] * q3 + t;
      acc[q] = t;
    }
    m = mn;
  }
  // tail: consume remaining prefetched edges one at a time
  for (int t = 0; j < je; j++, t++) {
    LV cv = (t == 0) ? pf0 : (t == 1) ? pf1 : pf2;
    float e = red16(edot(cv, xr2, att2));
    float mn = fmaxf(m, e);
    float a = __expf(m - mn);
    float p = __expf(e - mn);
    s = s * a + p;
    f16 ah = (f16)a, gh = (f16)p;
    f16x2 a2 = {ah, ah}, p2 = {gh, gh};
#pragma unroll
    for (int q = 0; q < 4; q++) acc[q] = acc[q] * a2 + cv.v[q] * p2;
    m = mn;
  }

  float inv = 1.f / s;
#pragma unroll
  for (int q = 0; q < 4; q++) {
    headout[h][dg * 4 + g][c0 + 2 * q] = (float)acc[q][0] * inv;
    headout[h][dg * 4 + g][c0 + 2 * q + 1] = (float)acc[q][1] * inv;
  }
  __syncthreads();
  for (int t = threadIdx.x; t < 4 * DG * DH; t += H * DG * 64) {
    int d = t >> 7, c = t & 127;
    float sum = 0.f;
#pragma unroll
    for (int q = 0; q < H; q++) sum += headout[q][d][c];
    float r = sum * (1.f / H) + bias[c];
    if (RELU) r = fmaxf(r, 0.f);
    int node = nodes[d];
    float o = r + (float)h_in[(size_t)node * DH + c];
    if (WF32) h_out[(size_t)node * DH + c] = o;
    else hh[(size_t)node * DH + c] = (f16)o;
  }
}

extern "C" void kernel_launch(void* const* d_in, const int* in_sizes, int n_in,
                              void* d_out, int out_size, void* d_ws, size_t ws_size,
                              hipStream_t stream) {
  const float* x = (const float*)d_in[0];
  const int* ei = (const int*)d_in[1];
  const float* Wl1 = (const float*)d_in[2];
  const float* Wr1 = (const float*)d_in[3];
  const float* att1 = (const float*)d_in[4];
  const float* b1 = (const float*)d_in[5];
  const float* Wl2 = (const float*)d_in[6];
  const float* Wr2 = (const float*)d_in[7];
  const float* att2 = (const float*)d_in[8];
  const float* b2 = (const float*)d_in[9];
  const float* Wl3 = (const float*)d_in[10];
  const float* Wr3 = (const float*)d_in[11];
  const float* att3 = (const float*)d_in[12];
  const float* b3 = (const float*)d_in[13];
  float* out = (float*)d_out;

  char* p = (char*)d_ws;
  u8* xl8  = (u8*)p;  p += (size_t)NN * 2048;   // fp8 xl|xr (all layers; L3 uses 1024B rows)
  f16* xh  = (f16*)p; p += (size_t)NN * DH * 2;
  f16* h1h = (f16*)p; p += (size_t)NN * DH * 2;
  f16* h2h = (f16*)p; p += (size_t)NN * DH * 2;
  f16* WT1 = (f16*)p; p += (size_t)2048 * 128 * 2;
  f16* WT2 = (f16*)p; p += (size_t)2048 * 128 * 2;
  f16* WT3 = (f16*)p; p += (size_t)1024 * 128 * 2;
  int* deg      = (int*)p; p += (size_t)NN * 4;
  int* cursor   = (int*)p; p += (size_t)NN * 4;
  int* rowstart = (int*)p; p += (size_t)(NN + 1) * 4;
  int* perm     = (int*)p; p += (size_t)NN * 4;
  int* bsum     = (int*)p; p += (size_t)32 * 4;
  int* ghist    = (int*)p; p += (size_t)20 * 64 * 4;
  int* csr      = (int*)p;

  const int* esrc = ei;
  const int* edst = ei + NE;

  const int nbc = (NN + 1023) / 1024;  // 20 CSR-build blocks

  hipMemsetAsync(deg, 0, sizeof(int) * 2 * NN, stream);  // deg + cursor
  conv_count_kernel<<<(NN * DH / 4 + 255) / 256, 256, 0, stream>>>(
      x, xh, NN * DH / 4, edst, deg, NE);
  csr_p1<<<nbc, 1024, 0, stream>>>(deg, rowstart, bsum, ghist, NN);
  csr_p3<<<nbc, 1024, 0, stream>>>(deg, rowstart, bsum, ghist, perm, NN, nbc);
  scatter_kernel<<<(NE + 255) / 256, 256, 0, stream>>>(esrc, edst, rowstart, cursor, csr, NE);
  sort_kernel<<<(NN * 16 + 255) / 256, 256, 0, stream>>>(rowstart, csr, perm, NN);
  transconv_all<<<dim3(32, 4, 6), 256, 0, stream>>>(
      Wl1, Wr1, Wl2, Wr2, Wl3, Wr3,
      WT1, WT1 + (size_t)1024 * 128, WT2, WT2 + (size_t)1024 * 128,
      WT3, WT3 + (size_t)512 * 128);

  const int nx = (NN + 127) / 128;  // 157

  // layer 1: fp8 rows 2048 B (xl 0-1023 | xr 1024-2047)
  gemm_f8<16><<<nx * 16, 256, 0, stream>>>(xh, WT1, xl8, NN);
  agg_kernel<8, 1, true, false, 11, 1024><<<NN / 4, 512, 0, stream>>>(
      xh, (const char*)xl8, att1, b1, csr, rowstart, perm, nullptr, h1h);
  // layer 2: same
  gemm_f8<16><<<nx * 16, 256, 0, stream>>>(h1h, WT2, xl8, NN);
  agg_kernel<8, 1, true, false, 11, 1024><<<NN / 4, 512, 0, stream>>>(
      h1h, (const char*)xl8, att2, b2, csr, rowstart, perm, nullptr, h2h);
  // layer 3: fp8 rows 1024 B (xl 0-511 | xr 512-1023), f32 output + residual
  gemm_f8<8><<<nx * 8, 256, 0, stream>>>(h2h, WT3, xl8, NN);
  agg_kernel<4, 2, false, true, 10, 512><<<NN / 8, 512, 0, stream>>>(
      h2h, (const char*)xl8, att3, b3, csr, rowstart, perm, out, nullptr);
}

// Round 22
// 283.619 us; speedup vs baseline: 1.1838x; 1.0116x over previous
//
#include <hip/hip_runtime.h>
#include <math.h>

#define NN 20000
#define NE 160000
#define DH 128

typedef _Float16 f16;
typedef f16 f16x2 __attribute__((ext_vector_type(2)));
typedef f16 f16x4 __attribute__((ext_vector_type(4)));
typedef f16 f16x8 __attribute__((ext_vector_type(8)));
typedef float f32x4 __attribute__((ext_vector_type(4)));
typedef unsigned int uint32;
typedef unsigned char u8;

// ---------------- prep: fused x->f16 convert + degree count + weight transpose ----
// blocks [0, NB_CONV): convert x to f16 and count degrees
// blocks [NB_CONV, NB_CONV+6*128): LDS tile-transpose of the six W matrices
#define NB_CONV 2500
__global__ __launch_bounds__(256) void prep_kernel(
    const float* __restrict__ X, f16* __restrict__ XH, int n4,
    const int* __restrict__ edst, int* __restrict__ deg, int ne,
    const float* __restrict__ W0, const float* __restrict__ W1,
    const float* __restrict__ W2, const float* __restrict__ W3,
    const float* __restrict__ W4, const float* __restrict__ W5,
    f16* O0, f16* O1, f16* O2, f16* O3, f16* O4, f16* O5) {
  int bid = blockIdx.x;
  if (bid < NB_CONV) {
    int i = bid * 256 + threadIdx.x;
    if (i < n4) {
      float4 v = *(const float4*)(X + (size_t)i * 4);
      f16x4 o = {(f16)v.x, (f16)v.y, (f16)v.z, (f16)v.w};
      *(f16x4*)(XH + (size_t)i * 4) = o;
    }
    if (i < ne) atomicAdd(&deg[edst[i]], 1);
    return;
  }
  int r = bid - NB_CONV;
  int z = r >> 7, sub = r & 127;  // z in 0..5, sub in 0..127
  const float* W; f16* O; int HC;
  switch (z) {
    case 0: W = W0; O = O0; HC = 1024; break;
    case 1: W = W1; O = O1; HC = 1024; break;
    case 2: W = W2; O = O2; HC = 1024; break;
    case 3: W = W3; O = O3; HC = 1024; break;
    case 4: W = W4; O = O4; HC = 512; break;
    default: W = W5; O = O5; HC = 512; break;
  }
  int c0 = (sub & 31) * 32;
  if (c0 >= HC) return;
  int k0 = (sub >> 5) * 32;
  __shared__ float t[32][33];
  int tx = threadIdx.x & 31, ty = threadIdx.x >> 5;  // 32 x 8
#pragma unroll
  for (int j = 0; j < 4; j++) {
    int k = k0 + ty + j * 8;
    t[ty + j * 8][tx] = W[(size_t)k * HC + c0 + tx];
  }
  __syncthreads();
#pragma unroll
  for (int j = 0; j < 4; j++) {
    int c = c0 + ty + j * 8;
    O[(size_t)c * 128 + k0 + tx] = (f16)t[tx][ty + j * 8];
  }
}

// ---------------- CSR build (2-phase) ----------------
__global__ __launch_bounds__(1024) void csr_p1(const int* __restrict__ deg,
                                               int* __restrict__ rowstart,
                                               int* __restrict__ bsum,
                                               int* __restrict__ ghist, int n) {
  __shared__ int wsum[16];
  __shared__ int lhist[64];
  const int tid = threadIdx.x;
  const int lane = tid & 63, w = tid >> 6;
  if (tid < 64) lhist[tid] = 0;
  __syncthreads();
  int i = blockIdx.x * 1024 + tid;
  int d = (i < n) ? deg[i] : 0;
  if (i < n) atomicAdd(&lhist[d < 63 ? d : 63], 1);
  int v = d;
#pragma unroll
  for (int off = 1; off < 64; off <<= 1) {
    int u = __shfl_up(v, off, 64);
    if (lane >= off) v += u;
  }
  if (lane == 63) wsum[w] = v;
  __syncthreads();
  if (w == 0) {
    int t = (lane < 16) ? wsum[lane] : 0;
#pragma unroll
    for (int off = 1; off < 16; off <<= 1) {
      int u = __shfl_up(t, off, 64);
      if (lane >= off) t += u;
    }
    if (lane < 16) wsum[lane] = t;
  }
  __syncthreads();
  int add = (w > 0 ? wsum[w - 1] : 0);
  if (i < n) rowstart[i + 1] = v + add;
  if (tid == 0) bsum[blockIdx.x] = wsum[15];
  if (tid < 64) ghist[blockIdx.x * 64 + tid] = lhist[tid];
}

__global__ __launch_bounds__(1024) void csr_p3(const int* __restrict__ deg,
                                               int* __restrict__ rowstart,
                                               const int* __restrict__ bsum,
                                               const int* __restrict__ ghist,
                                               int* __restrict__ perm, int n, int nb) {
  __shared__ int lcur[64];
  __shared__ int base[64];
  __shared__ int radd_s;
  const int tid = threadIdx.x;
  if (tid < 64) {
    lcur[tid] = 0;
    int pre = 0, tot = 0;
    for (int b = 0; b < nb; b++) {
      int v = ghist[b * 64 + tid];
      pre += (b < (int)blockIdx.x) ? v : 0;
      tot += v;
    }
    int incl = tot;
#pragma unroll
    for (int off = 1; off < 64; off <<= 1) {
      int u = __shfl_up(incl, off, 64);
      if (tid >= off) incl += u;
    }
    base[tid] = (n - incl) + pre;  // descending bucket start + within-bin prefix
  }
  if (tid == 0) {
    int r = 0;
    for (int b = 0; b < (int)blockIdx.x; b++) r += bsum[b];
    radd_s = r;
  }
  __syncthreads();
  int i = blockIdx.x * 1024 + tid;
  if (i < n) {
    rowstart[i + 1] += radd_s;
    int d = deg[i];
    int b = d < 63 ? d : 63;
    int pos = atomicAdd(&lcur[b], 1);
    perm[base[b] + pos] = i;
  }
  if (blockIdx.x == 0 && tid == 0) rowstart[0] = 0;
}

__global__ void scatter_kernel(const int* __restrict__ src, const int* __restrict__ dstp,
                               const int* __restrict__ rowstart, int* __restrict__ cursor,
                               int* __restrict__ csr, int n) {
  int i = blockIdx.x * blockDim.x + threadIdx.x;
  if (i < n) {
    int d = dstp[i];
    int pos = atomicAdd(&cursor[d], 1);
    csr[rowstart[d] + pos] = src[i];
  }
}

// one 16-lane subgroup per row; 16-element bitonic network.
__global__ void sort_kernel(const int* __restrict__ rowstart, int* __restrict__ csr,
                            const int* __restrict__ perm, int n) {
  int idx = blockIdx.x * blockDim.x + threadIdx.x;
  int sub = idx >> 4;
  int u = idx & 15;
  if (sub >= n) return;
  int i = perm[sub];
  int a = rowstart[i], b = rowstart[i + 1];
  int d = b - a;
  if (d <= 1) return;
  if (d <= 16) {
    int v = (u < d) ? csr[a + u] : 0x7FFFFFFF;
#pragma unroll
    for (int k = 2; k <= 16; k <<= 1) {
#pragma unroll
      for (int j = 16; j > 0; j >>= 1) {
        if (j > (k >> 1)) continue;
        int o = __shfl_xor(v, j, 64);
        bool takeMin = (((u & k) == 0) == ((u & j) == 0));
        v = takeMin ? (v < o ? v : o) : (v > o ? v : o);
      }
    }
    if (u < d) csr[a + u] = v;
  } else if (u == 0) {
    for (int j = a + 1; j < b; j++) {
      int v = csr[j];
      int k = j - 1;
      while (k >= a && csr[k] > v) { csr[k + 1] = csr[k]; k--; }
      csr[k + 1] = v;
    }
  }
}

// ---------------- f16 MFMA GEMM, whole-row fp8 output (R22: hoisted loads) ---
// R19 evidence: time ~ load-instruction count, all pipes idle -> per-wave load
// serialization suspected. Hoist ALL 32 fragment loads before any MFMA (vmcnt
// queue holds 32). VGPR ~210 -> 2 waves/SIMD, same measured residency as R17.
// MFMA order unchanged -> bitwise-identical C.
template <int YB>
__global__ __launch_bounds__(256) void gemm_f8(const f16* __restrict__ A,
                                               const f16* __restrict__ BT,
                                               u8* __restrict__ C8, int M) {
  const int ROWB = YB * 128;
  const int nx = (M + 127) / 128;
  const int chunk = nx * YB / 8;
  const int bid = blockIdx.x;
  const int p = (bid % 8) * chunk + bid / 8;
  const int bx = p / YB, by = p % YB;

  const int w = threadIdx.x >> 6, lane = threadIdx.x & 63;
  const int wm = w >> 1, wn = w & 1;
  const int row0 = bx * 128 + wm * 64;
  const int col0 = by * 128 + wn * 64;
  const int lr = lane & 15, lk = (lane >> 4) * 8;

  __shared__ f16 ct[128][144];

  f32x4 acc[4][4] = {};
  const f16* Arow[4];
  const f16* Brow[4];
#pragma unroll
  for (int m = 0; m < 4; m++) {
    int r = row0 + m * 16 + lr;
    r = r < M ? r : M - 1;
    Arow[m] = A + (size_t)r * 128 + lk;
  }
#pragma unroll
  for (int n = 0; n < 4; n++) {
    int c = col0 + n * 16 + lr;
    Brow[n] = BT + (size_t)c * 128 + lk;
  }
  // hoist all 32 fragment loads
  f16x8 a[4][4], b[4][4];  // [ks][m] / [ks][n]
#pragma unroll
  for (int ks = 0; ks < 4; ks++) {
#pragma unroll
    for (int m = 0; m < 4; m++) a[ks][m] = *(const f16x8*)(Arow[m] + ks * 32);
#pragma unroll
    for (int n = 0; n < 4; n++) b[ks][n] = *(const f16x8*)(Brow[n] + ks * 32);
  }
#pragma unroll
  for (int ks = 0; ks < 4; ks++)
#pragma unroll
    for (int m = 0; m < 4; m++)
#pragma unroll
      for (int n = 0; n < 4; n++)
        acc[m][n] = __builtin_amdgcn_mfma_f32_16x16x32_f16(a[ks][m], b[ks][n],
                                                           acc[m][n], 0, 0, 0);
  const int lrow = wm * 64, lcol = wn * 64;
#pragma unroll
  for (int m = 0; m < 4; m++) {
    int rbase = lrow + m * 16 + (lane >> 4) * 4;
#pragma unroll
    for (int r = 0; r < 4; r++) {
#pragma unroll
      for (int n = 0; n < 4; n++) {
        ct[rbase + r][lcol + n * 16 + lr] = (f16)acc[m][n][r];
      }
    }
  }
  __syncthreads();
  const int t = threadIdx.x;
  const int cidx = (t & 15) * 8;
  const int rowblk = bx * 128, colblk = by * 128;
#pragma unroll
  for (int rr = (t >> 4); rr < 128; rr += 16) {
    int gr = rowblk + rr;
    if (gr < M) {
      f16x8 v = *(const f16x8*)(&ct[rr][cidx]);
      int lo = __builtin_amdgcn_cvt_pk_fp8_f32((float)v[0], (float)v[1], 0, false);
      lo = __builtin_amdgcn_cvt_pk_fp8_f32((float)v[2], (float)v[3], lo, true);
      int hi = __builtin_amdgcn_cvt_pk_fp8_f32((float)v[4], (float)v[5], 0, false);
      hi = __builtin_amdgcn_cvt_pk_fp8_f32((float)v[6], (float)v[7], hi, true);
      uint2 o;
      o.x = (uint32)lo;
      o.y = (uint32)hi;
      *(uint2*)(C8 + (size_t)gr * ROWB + colblk + cidx) = o;
    }
  }
}

// ---------------- fused GATv2 aggregation ----------------
// NOTE (R14): persistent grid-stride agg REGRESSED; keep 1-shot blocks.
// NOTE (R11): 8-deep masked merge REGRESSED; keep 4-deep + scalar tail.
struct LV { f16x2 v[4]; };

// fp8-e4m3 gather: 8 bytes -> 8 f16 via HW cvt (exact embeddings).
__device__ __forceinline__ LV load8_f8(const char* __restrict__ base, uint32 off) {
  uint2 w = *(const uint2*)(base + off);
  auto a = __builtin_amdgcn_cvt_pk_f32_fp8((int)w.x, false);
  auto b = __builtin_amdgcn_cvt_pk_f32_fp8((int)w.x, true);
  auto c = __builtin_amdgcn_cvt_pk_f32_fp8((int)w.y, false);
  auto d = __builtin_amdgcn_cvt_pk_f32_fp8((int)w.y, true);
  LV o;
  o.v[0] = __builtin_bit_cast(f16x2, __builtin_amdgcn_cvt_pkrtz(a[0], a[1]));
  o.v[1] = __builtin_bit_cast(f16x2, __builtin_amdgcn_cvt_pkrtz(b[0], b[1]));
  o.v[2] = __builtin_bit_cast(f16x2, __builtin_amdgcn_cvt_pkrtz(c[0], c[1]));
  o.v[3] = __builtin_bit_cast(f16x2, __builtin_amdgcn_cvt_pkrtz(d[0], d[1]));
  return o;
}

__device__ __forceinline__ f16x2 leaky2(f16x2 z) {
  f16x2 zs = z * (f16)0.2f;
  return __builtin_elementwise_max(z, zs);
}

__device__ __forceinline__ float edot(const LV& x, const f16x2* xr2, const f16x2* att2) {
  float ea = 0.f, eb = 0.f;
  ea = __builtin_amdgcn_fdot2(leaky2(x.v[0] + xr2[0]), att2[0], ea, false);
  eb = __builtin_amdgcn_fdot2(leaky2(x.v[1] + xr2[1]), att2[1], eb, false);
  ea = __builtin_amdgcn_fdot2(leaky2(x.v[2] + xr2[2]), att2[2], ea, false);
  eb = __builtin_amdgcn_fdot2(leaky2(x.v[3] + xr2[3]), att2[3], eb, false);
  return ea + eb;
}

template <int PAT>
__device__ __forceinline__ float swz(float x) {
  return __int_as_float(__builtin_amdgcn_ds_swizzle(__float_as_int(x), PAT));
}

__device__ __forceinline__ void red16x4(float& a, float& b, float& c, float& d) {
  a += swz<0x041F>(a); b += swz<0x041F>(b); c += swz<0x041F>(c); d += swz<0x041F>(d);
  a += swz<0x081F>(a); b += swz<0x081F>(b); c += swz<0x081F>(c); d += swz<0x081F>(d);
  a += swz<0x101F>(a); b += swz<0x101F>(b); c += swz<0x101F>(c); d += swz<0x101F>(d);
  a += swz<0x201F>(a); b += swz<0x201F>(b); c += swz<0x201F>(c); d += swz<0x201F>(d);
}
__device__ __forceinline__ float red16(float a) {
  a += swz<0x041F>(a);
  a += swz<0x081F>(a);
  a += swz<0x101F>(a);
  a += swz<0x201F>(a);
  return a;
}

// H heads; DG dst-groups/block; LGROW: log2 fp8 row stride; XROFF: xr byte off.
template <int H, int DG, bool RELU, bool WF32, int LGROW, int XROFF>
__global__ __launch_bounds__(H * DG * 64) void agg_kernel(
    const f16* __restrict__ h_in, const char* __restrict__ xp,
    const float* __restrict__ att, const float* __restrict__ bias,
    const int* __restrict__ csr, const int* __restrict__ rowstart,
    const int* __restrict__ perm,
    float* __restrict__ h_out, f16* __restrict__ hh) {
  __shared__ float headout[H][4 * DG][DH];
  __shared__ int nodes[4 * DG];
  const int wv = threadIdx.x >> 6;
  const int h = wv & (H - 1);
  const int dg = wv / H;
  const int lane = threadIdx.x & 63;
  const int g = lane >> 4, u = lane & 15;
  const int c0 = u * 8;
  if (threadIdx.x < 4 * DG) nodes[threadIdx.x] = perm[blockIdx.x * 4 * DG + threadIdx.x];
  const int dst = perm[blockIdx.x * 4 * DG + dg * 4 + g];
  const uint32 loff = (uint32)(h * DH + c0);  // fp8: 1 byte/elem

  f16x2 att2[4], xr2[4];
  {
    const float* ap = att + h * DH + c0;
    float a0[8];
    *(float4*)a0 = *(const float4*)ap;
    *(float4*)(a0 + 4) = *(const float4*)(ap + 4);
#pragma unroll
    for (int q = 0; q < 4; q++) att2[q] = f16x2{(f16)a0[2 * q], (f16)a0[2 * q + 1]};
    LV xrv = load8_f8(xp, ((uint32)dst << LGROW) + XROFF + loff);
#pragma unroll
    for (int q = 0; q < 4; q++) xr2[q] = xrv.v[q];
  }

  const int js = rowstart[dst], je = rowstart[dst + 1];

  // self loop seed
  float m, s;
  f16x2 acc[4];
  {
    LV xv = load8_f8(xp, ((uint32)dst << LGROW) + loff);
    m = red16(edot(xv, xr2, att2));
    s = 1.f;
#pragma unroll
    for (int q = 0; q < 4; q++) acc[q] = xv.v[q];
  }

  // 4-deep prefetch over CSR row (indices clamped to je-1)
  LV pf0, pf1, pf2, pf3;
  {
    int ja = js < je ? js : je - 1;
    int jb = js + 1 < je ? js + 1 : je - 1;
    int jc = js + 2 < je ? js + 2 : je - 1;
    int jd = js + 3 < je ? js + 3 : je - 1;
    if (js < je) {
      pf0 = load8_f8(xp, ((uint32)csr[ja] << LGROW) + loff);
      pf1 = load8_f8(xp, ((uint32)csr[jb] << LGROW) + loff);
      pf2 = load8_f8(xp, ((uint32)csr[jc] << LGROW) + loff);
      pf3 = load8_f8(xp, ((uint32)csr[jd] << LGROW) + loff);
    }
  }

  int j = js;
  for (; j + 3 < je; j += 4) {
    LV cv0 = pf0, cv1 = pf1, cv2 = pf2, cv3 = pf3;
    int ja = j + 4 < je ? j + 4 : je - 1;
    int jb = j + 5 < je ? j + 5 : je - 1;
    int jc = j + 6 < je ? j + 6 : je - 1;
    int jd = j + 7 < je ? j + 7 : je - 1;
    pf0 = load8_f8(xp, ((uint32)csr[ja] << LGROW) + loff);
    pf1 = load8_f8(xp, ((uint32)csr[jb] << LGROW) + loff);
    pf2 = load8_f8(xp, ((uint32)csr[jc] << LGROW) + loff);
    pf3 = load8_f8(xp, ((uint32)csr[jd] << LGROW) + loff);

    float e0 = edot(cv0, xr2, att2);
    float e1 = edot(cv1, xr2, att2);
    float e2 = edot(cv2, xr2, att2);
    float e3 = edot(cv3, xr2, att2);
    red16x4(e0, e1, e2, e3);

    float mn = fmaxf(fmaxf(fmaxf(m, e0), fmaxf(e1, e2)), e3);
    float a = __expf(m - mn);
    float p0 = __expf(e0 - mn);
    float p1 = __expf(e1 - mn);
    float p2 = __expf(e2 - mn);
    float p3 = __expf(e3 - mn);
    s = s * a + ((p0 + p1) + (p2 + p3));
    f16 ah = (f16)a, g0 = (f16)p0, g1 = (f16)p1, g2 = (f16)p2, g3 = (f16)p3;
    f16x2 a2 = {ah, ah}, q0 = {g0, g0}, q1 = {g1, g1}, q2 = {g2, g2}, q3 = {g3, g3};
#pragma unroll
    for (int q = 0; q < 4; q++) {
      f16x2 t = acc[q] * a2;
      t = cv0.v[q] * q0 + t;
      t = cv1.v[q] * q1 + t;
      t = cv2.v[q] * q2 + t;
      t = cv3.v[q] * q3 + t;
      acc[q] = t;
    }
    m = mn;
  }
  // tail: consume remaining prefetched edges one at a time
  for (int t = 0; j < je; j++, t++) {
    LV cv = (t == 0) ? pf0 : (t == 1) ? pf1 : pf2;
    float e = red16(edot(cv, xr2, att2));
    float mn = fmaxf(m, e);
    float a = __expf(m - mn);
    float p = __expf(e - mn);
    s = s * a + p;
    f16 ah = (f16)a, gh = (f16)p;
    f16x2 a2 = {ah, ah}, p2 = {gh, gh};
#pragma unroll
    for (int q = 0; q < 4; q++) acc[q] = acc[q] * a2 + cv.v[q] * p2;
    m = mn;
  }

  float inv = 1.f / s;
#pragma unroll
  for (int q = 0; q < 4; q++) {
    headout[h][dg * 4 + g][c0 + 2 * q] = (float)acc[q][0] * inv;
    headout[h][dg * 4 + g][c0 + 2 * q + 1] = (float)acc[q][1] * inv;
  }
  __syncthreads();
  for (int t = threadIdx.x; t < 4 * DG * DH; t += H * DG * 64) {
    int d = t >> 7, c = t & 127;
    float sum = 0.f;
#pragma unroll
    for (int q = 0; q < H; q++) sum += headout[q][d][c];
    float r = sum * (1.f / H) + bias[c];
    if (RELU) r = fmaxf(r, 0.f);
    int node = nodes[d];
    float o = r + (float)h_in[(size_t)node * DH + c];
    if (WF32) h_out[(size_t)node * DH + c] = o;
    else hh[(size_t)node * DH + c] = (f16)o;
  }
}

extern "C" void kernel_launch(void* const* d_in, const int* in_sizes, int n_in,
                              void* d_out, int out_size, void* d_ws, size_t ws_size,
                              hipStream_t stream) {
  const float* x = (const float*)d_in[0];
  const int* ei = (const int*)d_in[1];
  const float* Wl1 = (const float*)d_in[2];
  const float* Wr1 = (const float*)d_in[3];
  const float* att1 = (const float*)d_in[4];
  const float* b1 = (const float*)d_in[5];
  const float* Wl2 = (const float*)d_in[6];
  const float* Wr2 = (const float*)d_in[7];
  const float* att2 = (const float*)d_in[8];
  const float* b2 = (const float*)d_in[9];
  const float* Wl3 = (const float*)d_in[10];
  const float* Wr3 = (const float*)d_in[11];
  const float* att3 = (const float*)d_in[12];
  const float* b3 = (const float*)d_in[13];
  float* out = (float*)d_out;

  char* p = (char*)d_ws;
  u8* xl8  = (u8*)p;  p += (size_t)NN * 2048;   // fp8 xl|xr (all layers)
  f16* xh  = (f16*)p; p += (size_t)NN * DH * 2;
  f16* h1h = (f16*)p; p += (size_t)NN * DH * 2;
  f16* h2h = (f16*)p; p += (size_t)NN * DH * 2;
  f16* WT1 = (f16*)p; p += (size_t)2048 * 128 * 2;
  f16* WT2 = (f16*)p; p += (size_t)2048 * 128 * 2;
  f16* WT3 = (f16*)p; p += (size_t)1024 * 128 * 2;
  int* deg      = (int*)p; p += (size_t)NN * 4;
  int* cursor   = (int*)p; p += (size_t)NN * 4;
  int* rowstart = (int*)p; p += (size_t)(NN + 1) * 4;
  int* perm     = (int*)p; p += (size_t)NN * 4;
  int* bsum     = (int*)p; p += (size_t)32 * 4;
  int* ghist    = (int*)p; p += (size_t)20 * 64 * 4;
  int* csr      = (int*)p;

  const int* esrc = ei;
  const int* edst = ei + NE;

  const int nbc = (NN + 1023) / 1024;  // 20 CSR-build blocks

  hipMemsetAsync(deg, 0, sizeof(int) * 2 * NN, stream);  // deg + cursor
  prep_kernel<<<NB_CONV + 6 * 128, 256, 0, stream>>>(
      x, xh, NN * DH / 4, edst, deg, NE,
      Wl1, Wr1, Wl2, Wr2, Wl3, Wr3,
      WT1, WT1 + (size_t)1024 * 128, WT2, WT2 + (size_t)1024 * 128,
      WT3, WT3 + (size_t)512 * 128);
  csr_p1<<<nbc, 1024, 0, stream>>>(deg, rowstart, bsum, ghist, NN);
  csr_p3<<<nbc, 1024, 0, stream>>>(deg, rowstart, bsum, ghist, perm, NN, nbc);
  scatter_kernel<<<(NE + 255) / 256, 256, 0, stream>>>(esrc, edst, rowstart, cursor, csr, NE);
  sort_kernel<<<(NN * 16 + 255) / 256, 256, 0, stream>>>(rowstart, csr, perm, NN);

  const int nx = (NN + 127) / 128;  // 157

  // layer 1: fp8 rows 2048 B (xl 0-1023 | xr 1024-2047)
  gemm_f8<16><<<nx * 16, 256, 0, stream>>>(xh, WT1, xl8, NN);
  agg_kernel<8, 1, true, false, 11, 1024><<<NN / 4, 512, 0, stream>>>(
      xh, (const char*)xl8, att1, b1, csr, rowstart, perm, nullptr, h1h);
  // layer 2: same
  gemm_f8<16><<<nx * 16, 256, 0, stream>>>(h1h, WT2, xl8, NN);
  agg_kernel<8, 1, true, false, 11, 1024><<<NN / 4, 512, 0, stream>>>(
      h1h, (const char*)xl8, att2, b2, csr, rowstart, perm, nullptr, h2h);
  // layer 3: fp8 rows 1024 B (xl 0-511 | xr 512-1023), f32 output + residual
  gemm_f8<8><<<nx * 8, 256, 0, stream>>>(h2h, WT3, xl8, NN);
  agg_kernel<4, 2, false, true, 10, 512><<<NN / 8, 512, 0, stream>>>(
      h2h, (const char*)xl8, att3, b3, csr, rowstart, perm, out, nullptr);
}

// Round 23
// 278.115 us; speedup vs baseline: 1.2072x; 1.0198x over previous
//
#include <hip/hip_runtime.h>
#include <math.h>

#define NN 20000
#define NE 160000
#define DH 128

typedef _Float16 f16;
typedef f16 f16x2 __attribute__((ext_vector_type(2)));
typedef f16 f16x4 __attribute__((ext_vector_type(4)));
typedef f16 f16x8 __attribute__((ext_vector_type(8)));
typedef float f32x4 __attribute__((ext_vector_type(4)));
typedef unsigned int uint32;
typedef unsigned char u8;

// ---------------- prep: fused x->f16 convert + degree count + weight transpose ----
#define NB_CONV 2500
__global__ __launch_bounds__(256) void prep_kernel(
    const float* __restrict__ X, f16* __restrict__ XH, int n4,
    const int* __restrict__ edst, int* __restrict__ deg, int ne,
    const float* __restrict__ W0, const float* __restrict__ W1,
    const float* __restrict__ W2, const float* __restrict__ W3,
    const float* __restrict__ W4, const float* __restrict__ W5,
    f16* O0, f16* O1, f16* O2, f16* O3, f16* O4, f16* O5) {
  int bid = blockIdx.x;
  if (bid < NB_CONV) {
    int i = bid * 256 + threadIdx.x;
    if (i < n4) {
      float4 v = *(const float4*)(X + (size_t)i * 4);
      f16x4 o = {(f16)v.x, (f16)v.y, (f16)v.z, (f16)v.w};
      *(f16x4*)(XH + (size_t)i * 4) = o;
    }
    if (i < ne) atomicAdd(&deg[edst[i]], 1);
    return;
  }
  int r = bid - NB_CONV;
  int z = r >> 7, sub = r & 127;
  const float* W; f16* O; int HC;
  switch (z) {
    case 0: W = W0; O = O0; HC = 1024; break;
    case 1: W = W1; O = O1; HC = 1024; break;
    case 2: W = W2; O = O2; HC = 1024; break;
    case 3: W = W3; O = O3; HC = 1024; break;
    case 4: W = W4; O = O4; HC = 512; break;
    default: W = W5; O = O5; HC = 512; break;
  }
  int c0 = (sub & 31) * 32;
  if (c0 >= HC) return;
  int k0 = (sub >> 5) * 32;
  __shared__ float t[32][33];
  int tx = threadIdx.x & 31, ty = threadIdx.x >> 5;
#pragma unroll
  for (int j = 0; j < 4; j++) {
    int k = k0 + ty + j * 8;
    t[ty + j * 8][tx] = W[(size_t)k * HC + c0 + tx];
  }
  __syncthreads();
#pragma unroll
  for (int j = 0; j < 4; j++) {
    int c = c0 + ty + j * 8;
    O[(size_t)c * 128 + k0 + tx] = (f16)t[tx][ty + j * 8];
  }
}

// ---------------- CSR build (2-phase) ----------------
__global__ __launch_bounds__(1024) void csr_p1(const int* __restrict__ deg,
                                               int* __restrict__ rowstart,
                                               int* __restrict__ bsum,
                                               int* __restrict__ ghist, int n) {
  __shared__ int wsum[16];
  __shared__ int lhist[64];
  const int tid = threadIdx.x;
  const int lane = tid & 63, w = tid >> 6;
  if (tid < 64) lhist[tid] = 0;
  __syncthreads();
  int i = blockIdx.x * 1024 + tid;
  int d = (i < n) ? deg[i] : 0;
  if (i < n) atomicAdd(&lhist[d < 63 ? d : 63], 1);
  int v = d;
#pragma unroll
  for (int off = 1; off < 64; off <<= 1) {
    int u = __shfl_up(v, off, 64);
    if (lane >= off) v += u;
  }
  if (lane == 63) wsum[w] = v;
  __syncthreads();
  if (w == 0) {
    int t = (lane < 16) ? wsum[lane] : 0;
#pragma unroll
    for (int off = 1; off < 16; off <<= 1) {
      int u = __shfl_up(t, off, 64);
      if (lane >= off) t += u;
    }
    if (lane < 16) wsum[lane] = t;
  }
  __syncthreads();
  int add = (w > 0 ? wsum[w - 1] : 0);
  if (i < n) rowstart[i + 1] = v + add;
  if (tid == 0) bsum[blockIdx.x] = wsum[15];
  if (tid < 64) ghist[blockIdx.x * 64 + tid] = lhist[tid];
}

__global__ __launch_bounds__(1024) void csr_p3(const int* __restrict__ deg,
                                               int* __restrict__ rowstart,
                                               const int* __restrict__ bsum,
                                               const int* __restrict__ ghist,
                                               int* __restrict__ perm, int n, int nb) {
  __shared__ int lcur[64];
  __shared__ int base[64];
  __shared__ int radd_s;
  const int tid = threadIdx.x;
  if (tid < 64) {
    lcur[tid] = 0;
    int pre = 0, tot = 0;
    for (int b = 0; b < nb; b++) {
      int v = ghist[b * 64 + tid];
      pre += (b < (int)blockIdx.x) ? v : 0;
      tot += v;
    }
    int incl = tot;
#pragma unroll
    for (int off = 1; off < 64; off <<= 1) {
      int u = __shfl_up(incl, off, 64);
      if (tid >= off) incl += u;
    }
    base[tid] = (n - incl) + pre;
  }
  if (tid == 0) {
    int r = 0;
    for (int b = 0; b < (int)blockIdx.x; b++) r += bsum[b];
    radd_s = r;
  }
  __syncthreads();
  int i = blockIdx.x * 1024 + tid;
  if (i < n) {
    rowstart[i + 1] += radd_s;
    int d = deg[i];
    int b = d < 63 ? d : 63;
    int pos = atomicAdd(&lcur[b], 1);
    perm[base[b] + pos] = i;
  }
  if (blockIdx.x == 0 && tid == 0) rowstart[0] = 0;
}

__global__ void scatter_kernel(const int* __restrict__ src, const int* __restrict__ dstp,
                               const int* __restrict__ rowstart, int* __restrict__ cursor,
                               int* __restrict__ csr, int n) {
  int i = blockIdx.x * blockDim.x + threadIdx.x;
  if (i < n) {
    int d = dstp[i];
    int pos = atomicAdd(&cursor[d], 1);
    csr[rowstart[d] + pos] = src[i];
  }
}

// sort body: one 16-lane subgroup per row; 16-element bitonic network.
__device__ __forceinline__ void sort_body(const int* __restrict__ rowstart,
                                          int* __restrict__ csr,
                                          const int* __restrict__ perm,
                                          int idx, int n) {
  int sub = idx >> 4;
  int u = idx & 15;
  if (sub >= n) return;
  int i = perm[sub];
  int a = rowstart[i], b = rowstart[i + 1];
  int d = b - a;
  if (d <= 1) return;
  if (d <= 16) {
    int v = (u < d) ? csr[a + u] : 0x7FFFFFFF;
#pragma unroll
    for (int k = 2; k <= 16; k <<= 1) {
#pragma unroll
      for (int j = 16; j > 0; j >>= 1) {
        if (j > (k >> 1)) continue;
        int o = __shfl_xor(v, j, 64);
        bool takeMin = (((u & k) == 0) == ((u & j) == 0));
        v = takeMin ? (v < o ? v : o) : (v > o ? v : o);
      }
    }
    if (u < d) csr[a + u] = v;
  } else if (u == 0) {
    for (int j = a + 1; j < b; j++) {
      int v = csr[j];
      int k = j - 1;
      while (k >= a && csr[k] > v) { csr[k + 1] = csr[k]; k--; }
      csr[k + 1] = v;
    }
  }
}

// ---------------- f16 MFMA GEMM body, whole-row fp8 output ----------------
// R17-R22 GEMM ladder: one-pass fragment-direct = best (46.6us); retile,
// LDS-staging, two-pass epilogue, hoisted loads all null-or-worse. Floor
// mechanism unidentified from available counters -- structure FROZEN.
template <int YB>
__device__ __forceinline__ void gemm_f8_body(const f16* __restrict__ A,
                                             const f16* __restrict__ BT,
                                             u8* __restrict__ C8, int M, int bid,
                                             f16 (*ct)[144]) {
  const int ROWB = YB * 128;
  const int nx = (M + 127) / 128;
  const int chunk = nx * YB / 8;
  const int p = (bid % 8) * chunk + bid / 8;
  const int bx = p / YB, by = p % YB;

  const int w = threadIdx.x >> 6, lane = threadIdx.x & 63;
  const int wm = w >> 1, wn = w & 1;
  const int row0 = bx * 128 + wm * 64;
  const int col0 = by * 128 + wn * 64;
  const int lr = lane & 15, lk = (lane >> 4) * 8;

  f32x4 acc[4][4] = {};
  const f16* Arow[4];
  const f16* Brow[4];
#pragma unroll
  for (int m = 0; m < 4; m++) {
    int r = row0 + m * 16 + lr;
    r = r < M ? r : M - 1;
    Arow[m] = A + (size_t)r * 128 + lk;
  }
#pragma unroll
  for (int n = 0; n < 4; n++) {
    int c = col0 + n * 16 + lr;
    Brow[n] = BT + (size_t)c * 128 + lk;
  }
  f16x8 a[4][4], b[4][4];  // hoisted [ks][m]/[ks][n]
#pragma unroll
  for (int ks = 0; ks < 4; ks++) {
#pragma unroll
    for (int m = 0; m < 4; m++) a[ks][m] = *(const f16x8*)(Arow[m] + ks * 32);
#pragma unroll
    for (int n = 0; n < 4; n++) b[ks][n] = *(const f16x8*)(Brow[n] + ks * 32);
  }
#pragma unroll
  for (int ks = 0; ks < 4; ks++)
#pragma unroll
    for (int m = 0; m < 4; m++)
#pragma unroll
      for (int n = 0; n < 4; n++)
        acc[m][n] = __builtin_amdgcn_mfma_f32_16x16x32_f16(a[ks][m], b[ks][n],
                                                           acc[m][n], 0, 0, 0);
  const int lrow = wm * 64, lcol = wn * 64;
#pragma unroll
  for (int m = 0; m < 4; m++) {
    int rbase = lrow + m * 16 + (lane >> 4) * 4;
#pragma unroll
    for (int r = 0; r < 4; r++) {
#pragma unroll
      for (int n = 0; n < 4; n++) {
        ct[rbase + r][lcol + n * 16 + lr] = (f16)acc[m][n][r];
      }
    }
  }
  __syncthreads();
  const int t = threadIdx.x;
  const int cidx = (t & 15) * 8;
  const int rowblk = bx * 128, colblk = by * 128;
#pragma unroll
  for (int rr = (t >> 4); rr < 128; rr += 16) {
    int gr = rowblk + rr;
    if (gr < M) {
      f16x8 v = *(const f16x8*)(&ct[rr][cidx]);
      int lo = __builtin_amdgcn_cvt_pk_fp8_f32((float)v[0], (float)v[1], 0, false);
      lo = __builtin_amdgcn_cvt_pk_fp8_f32((float)v[2], (float)v[3], lo, true);
      int hi = __builtin_amdgcn_cvt_pk_fp8_f32((float)v[4], (float)v[5], 0, false);
      hi = __builtin_amdgcn_cvt_pk_fp8_f32((float)v[6], (float)v[7], hi, true);
      uint2 o;
      o.x = (uint32)lo;
      o.y = (uint32)hi;
      *(uint2*)(C8 + (size_t)gr * ROWB + colblk + cidx) = o;
    }
  }
}

template <int YB>
__global__ __launch_bounds__(256) void gemm_f8(const f16* __restrict__ A,
                                               const f16* __restrict__ BT,
                                               u8* __restrict__ C8, int M) {
  __shared__ f16 ct[128][144];
  gemm_f8_body<YB>(A, BT, C8, M, blockIdx.x, ct);
}

// fused: blocks [0, NGEMM) run layer-1 GEMM; blocks [NGEMM, ...) run sort.
// sort depends only on scatter (prior launch); gemm depends only on prep.
template <int YB>
__global__ __launch_bounds__(256) void gemm_sort_kernel(
    const f16* __restrict__ A, const f16* __restrict__ BT, u8* __restrict__ C8,
    int M, int ngemm, const int* __restrict__ rowstart, int* __restrict__ csr,
    const int* __restrict__ perm, int n) {
  __shared__ f16 ct[128][144];
  int bid = blockIdx.x;
  if (bid < ngemm) {
    gemm_f8_body<YB>(A, BT, C8, M, bid, ct);
  } else {
    int idx = (bid - ngemm) * 256 + threadIdx.x;
    sort_body(rowstart, csr, perm, idx, n);
  }
}

// ---------------- fused GATv2 aggregation ----------------
// NOTE (R14): persistent grid-stride agg REGRESSED; keep 1-shot blocks.
// NOTE (R11): 8-deep masked merge REGRESSED; keep 4-deep + scalar tail.
struct LV { f16x2 v[4]; };

// fp8-e4m3 gather: 8 bytes -> 8 f16 via HW cvt (exact embeddings).
__device__ __forceinline__ LV load8_f8(const char* __restrict__ base, uint32 off) {
  uint2 w = *(const uint2*)(base + off);
  auto a = __builtin_amdgcn_cvt_pk_f32_fp8((int)w.x, false);
  auto b = __builtin_amdgcn_cvt_pk_f32_fp8((int)w.x, true);
  auto c = __builtin_amdgcn_cvt_pk_f32_fp8((int)w.y, false);
  auto d = __builtin_amdgcn_cvt_pk_f32_fp8((int)w.y, true);
  LV o;
  o.v[0] = __builtin_bit_cast(f16x2, __builtin_amdgcn_cvt_pkrtz(a[0], a[1]));
  o.v[1] = __builtin_bit_cast(f16x2, __builtin_amdgcn_cvt_pkrtz(b[0], b[1]));
  o.v[2] = __builtin_bit_cast(f16x2, __builtin_amdgcn_cvt_pkrtz(c[0], c[1]));
  o.v[3] = __builtin_bit_cast(f16x2, __builtin_amdgcn_cvt_pkrtz(d[0], d[1]));
  return o;
}

__device__ __forceinline__ f16x2 leaky2(f16x2 z) {
  f16x2 zs = z * (f16)0.2f;
  return __builtin_elementwise_max(z, zs);
}

__device__ __forceinline__ float edot(const LV& x, const f16x2* xr2, const f16x2* att2) {
  float ea = 0.f, eb = 0.f;
  ea = __builtin_amdgcn_fdot2(leaky2(x.v[0] + xr2[0]), att2[0], ea, false);
  eb = __builtin_amdgcn_fdot2(leaky2(x.v[1] + xr2[1]), att2[1], eb, false);
  ea = __builtin_amdgcn_fdot2(leaky2(x.v[2] + xr2[2]), att2[2], ea, false);
  eb = __builtin_amdgcn_fdot2(leaky2(x.v[3] + xr2[3]), att2[3], eb, false);
  return ea + eb;
}

template <int PAT>
__device__ __forceinline__ float swz(float x) {
  return __int_as_float(__builtin_amdgcn_ds_swizzle(__float_as_int(x), PAT));
}

__device__ __forceinline__ void red16x4(float& a, float& b, float& c, float& d) {
  a += swz<0x041F>(a); b += swz<0x041F>(b); c += swz<0x041F>(c); d += swz<0x041F>(d);
  a += swz<0x081F>(a); b += swz<0x081F>(b); c += swz<0x081F>(c); d += swz<0x081F>(d);
  a += swz<0x101F>(a); b += swz<0x101F>(b); c += swz<0x101F>(c); d += swz<0x101F>(d);
  a += swz<0x201F>(a); b += swz<0x201F>(b); c += swz<0x201F>(c); d += swz<0x201F>(d);
}
__device__ __forceinline__ float red16(float a) {
  a += swz<0x041F>(a);
  a += swz<0x081F>(a);
  a += swz<0x101F>(a);
  a += swz<0x201F>(a);
  return a;
}

// H heads; DG dst-groups/block; LGROW: log2 fp8 row stride; XROFF: xr byte off.
template <int H, int DG, bool RELU, bool WF32, int LGROW, int XROFF>
__global__ __launch_bounds__(H * DG * 64) void agg_kernel(
    const f16* __restrict__ h_in, const char* __restrict__ xp,
    const float* __restrict__ att, const float* __restrict__ bias,
    const int* __restrict__ csr, const int* __restrict__ rowstart,
    const int* __restrict__ perm,
    float* __restrict__ h_out, f16* __restrict__ hh) {
  __shared__ float headout[H][4 * DG][DH];
  __shared__ int nodes[4 * DG];
  const int wv = threadIdx.x >> 6;
  const int h = wv & (H - 1);
  const int dg = wv / H;
  const int lane = threadIdx.x & 63;
  const int g = lane >> 4, u = lane & 15;
  const int c0 = u * 8;
  if (threadIdx.x < 4 * DG) nodes[threadIdx.x] = perm[blockIdx.x * 4 * DG + threadIdx.x];
  const int dst = perm[blockIdx.x * 4 * DG + dg * 4 + g];
  const uint32 loff = (uint32)(h * DH + c0);  // fp8: 1 byte/elem

  f16x2 att2[4], xr2[4];
  {
    const float* ap = att + h * DH + c0;
    float a0[8];
    *(float4*)a0 = *(const float4*)ap;
    *(float4*)(a0 + 4) = *(const float4*)(ap + 4);
#pragma unroll
    for (int q = 0; q < 4; q++) att2[q] = f16x2{(f16)a0[2 * q], (f16)a0[2 * q + 1]};
    LV xrv = load8_f8(xp, ((uint32)dst << LGROW) + XROFF + loff);
#pragma unroll
    for (int q = 0; q < 4; q++) xr2[q] = xrv.v[q];
  }

  const int js = rowstart[dst], je = rowstart[dst + 1];

  // self loop seed
  float m, s;
  f16x2 acc[4];
  {
    LV xv = load8_f8(xp, ((uint32)dst << LGROW) + loff);
    m = red16(edot(xv, xr2, att2));
    s = 1.f;
#pragma unroll
    for (int q = 0; q < 4; q++) acc[q] = xv.v[q];
  }

  // 4-deep prefetch over CSR row (indices clamped to je-1)
  LV pf0, pf1, pf2, pf3;
  {
    int ja = js < je ? js : je - 1;
    int jb = js + 1 < je ? js + 1 : je - 1;
    int jc = js + 2 < je ? js + 2 : je - 1;
    int jd = js + 3 < je ? js + 3 : je - 1;
    if (js < je) {
      pf0 = load8_f8(xp, ((uint32)csr[ja] << LGROW) + loff);
      pf1 = load8_f8(xp, ((uint32)csr[jb] << LGROW) + loff);
      pf2 = load8_f8(xp, ((uint32)csr[jc] << LGROW) + loff);
      pf3 = load8_f8(xp, ((uint32)csr[jd] << LGROW) + loff);
    }
  }

  int j = js;
  for (; j + 3 < je; j += 4) {
    LV cv0 = pf0, cv1 = pf1, cv2 = pf2, cv3 = pf3;
    int ja = j + 4 < je ? j + 4 : je - 1;
    int jb = j + 5 < je ? j + 5 : je - 1;
    int jc = j + 6 < je ? j + 6 : je - 1;
    int jd = j + 7 < je ? j + 7 : je - 1;
    pf0 = load8_f8(xp, ((uint32)csr[ja] << LGROW) + loff);
    pf1 = load8_f8(xp, ((uint32)csr[jb] << LGROW) + loff);
    pf2 = load8_f8(xp, ((uint32)csr[jc] << LGROW) + loff);
    pf3 = load8_f8(xp, ((uint32)csr[jd] << LGROW) + loff);

    float e0 = edot(cv0, xr2, att2);
    float e1 = edot(cv1, xr2, att2);
    float e2 = edot(cv2, xr2, att2);
    float e3 = edot(cv3, xr2, att2);
    red16x4(e0, e1, e2, e3);

    float mn = fmaxf(fmaxf(fmaxf(m, e0), fmaxf(e1, e2)), e3);
    float a = __expf(m - mn);
    float p0 = __expf(e0 - mn);
    float p1 = __expf(e1 - mn);
    float p2 = __expf(e2 - mn);
    float p3 = __expf(e3 - mn);
    s = s * a + ((p0 + p1) + (p2 + p3));
    f16 ah = (f16)a, g0 = (f16)p0, g1 = (f16)p1, g2 = (f16)p2, g3 = (f16)p3;
    f16x2 a2 = {ah, ah}, q0 = {g0, g0}, q1 = {g1, g1}, q2 = {g2, g2}, q3 = {g3, g3};
#pragma unroll
    for (int q = 0; q < 4; q++) {
      f16x2 t = acc[q] * a2;
      t = cv0.v[q] * q0 + t;
      t = cv1.v[q] * q1 + t;
      t = cv2.v[q] * q2 + t;
      t = cv3.v[q] * q3 + t;
      acc[q] = t;
    }
    m = mn;
  }
  // tail: consume remaining prefetched edges one at a time
  for (int t = 0; j < je; j++, t++) {
    LV cv = (t == 0) ? pf0 : (t == 1) ? pf1 : pf2;
    float e = red16(edot(cv, xr2, att2));
    float mn = fmaxf(m, e);
    float a = __expf(m - mn);
    float p = __expf(e - mn);
    s = s * a + p;
    f16 ah = (f16)a, gh = (f16)p;
    f16x2 a2 = {ah, ah}, p2 = {gh, gh};
#pragma unroll
    for (int q = 0; q < 4; q++) acc[q] = acc[q] * a2 + cv.v[q] * p2;
    m = mn;
  }

  float inv = 1.f / s;
#pragma unroll
  for (int q = 0; q < 4; q++) {
    headout[h][dg * 4 + g][c0 + 2 * q] = (float)acc[q][0] * inv;
    headout[h][dg * 4 + g][c0 + 2 * q + 1] = (float)acc[q][1] * inv;
  }
  __syncthreads();
  for (int t = threadIdx.x; t < 4 * DG * DH; t += H * DG * 64) {
    int d = t >> 7, c = t & 127;
    float sum = 0.f;
#pragma unroll
    for (int q = 0; q < H; q++) sum += headout[q][d][c];
    float r = sum * (1.f / H) + bias[c];
    if (RELU) r = fmaxf(r, 0.f);
    int node = nodes[d];
    float o = r + (float)h_in[(size_t)node * DH + c];
    if (WF32) h_out[(size_t)node * DH + c] = o;
    else hh[(size_t)node * DH + c] = (f16)o;
  }
}

extern "C" void kernel_launch(void* const* d_in, const int* in_sizes, int n_in,
                              void* d_out, int out_size, void* d_ws, size_t ws_size,
                              hipStream_t stream) {
  const float* x = (const float*)d_in[0];
  const int* ei = (const int*)d_in[1];
  const float* Wl1 = (const float*)d_in[2];
  const float* Wr1 = (const float*)d_in[3];
  const float* att1 = (const float*)d_in[4];
  const float* b1 = (const float*)d_in[5];
  const float* Wl2 = (const float*)d_in[6];
  const float* Wr2 = (const float*)d_in[7];
  const float* att2 = (const float*)d_in[8];
  const float* b2 = (const float*)d_in[9];
  const float* Wl3 = (const float*)d_in[10];
  const float* Wr3 = (const float*)d_in[11];
  const float* att3 = (const float*)d_in[12];
  const float* b3 = (const float*)d_in[13];
  float* out = (float*)d_out;

  char* p = (char*)d_ws;
  u8* xl8  = (u8*)p;  p += (size_t)NN * 2048;   // fp8 xl|xr (all layers)
  f16* xh  = (f16*)p; p += (size_t)NN * DH * 2;
  f16* h1h = (f16*)p; p += (size_t)NN * DH * 2;
  f16* h2h = (f16*)p; p += (size_t)NN * DH * 2;
  f16* WT1 = (f16*)p; p += (size_t)2048 * 128 * 2;
  f16* WT2 = (f16*)p; p += (size_t)2048 * 128 * 2;
  f16* WT3 = (f16*)p; p += (size_t)1024 * 128 * 2;
  int* deg      = (int*)p; p += (size_t)NN * 4;
  int* cursor   = (int*)p; p += (size_t)NN * 4;
  int* rowstart = (int*)p; p += (size_t)(NN + 1) * 4;
  int* perm     = (int*)p; p += (size_t)NN * 4;
  int* bsum     = (int*)p; p += (size_t)32 * 4;
  int* ghist    = (int*)p; p += (size_t)20 * 64 * 4;
  int* csr      = (int*)p;

  const int* esrc = ei;
  const int* edst = ei + NE;

  const int nbc = (NN + 1023) / 1024;  // 20 CSR-build blocks

  hipMemsetAsync(deg, 0, sizeof(int) * 2 * NN, stream);  // deg + cursor
  prep_kernel<<<NB_CONV + 6 * 128, 256, 0, stream>>>(
      x, xh, NN * DH / 4, edst, deg, NE,
      Wl1, Wr1, Wl2, Wr2, Wl3, Wr3,
      WT1, WT1 + (size_t)1024 * 128, WT2, WT2 + (size_t)1024 * 128,
      WT3, WT3 + (size_t)512 * 128);
  csr_p1<<<nbc, 1024, 0, stream>>>(deg, rowstart, bsum, ghist, NN);
  csr_p3<<<nbc, 1024, 0, stream>>>(deg, rowstart, bsum, ghist, perm, NN, nbc);
  scatter_kernel<<<(NE + 255) / 256, 256, 0, stream>>>(esrc, edst, rowstart, cursor, csr, NE);

  const int nx = (NN + 127) / 128;  // 157
  const int ngemm1 = nx * 16;       // 2512
  const int nsort = (NN * 16 + 255) / 256;  // 1250

  // layer 1: [gemm1 || sort] — sort depends on scatter (done), gemm on prep (done)
  gemm_sort_kernel<16><<<ngemm1 + nsort, 256, 0, stream>>>(
      xh, WT1, xl8, NN, ngemm1, rowstart, csr, perm, NN);
  agg_kernel<8, 1, true, false, 11, 1024><<<NN / 4, 512, 0, stream>>>(
      xh, (const char*)xl8, att1, b1, csr, rowstart, perm, nullptr, h1h);
  // layer 2
  gemm_f8<16><<<nx * 16, 256, 0, stream>>>(h1h, WT2, xl8, NN);
  agg_kernel<8, 1, true, false, 11, 1024><<<NN / 4, 512, 0, stream>>>(
      h1h, (const char*)xl8, att2, b2, csr, rowstart, perm, nullptr, h2h);
  // layer 3: fp8 rows 1024 B (xl 0-511 | xr 512-1023), f32 output + residual
  gemm_f8<8><<<nx * 8, 256, 0, stream>>>(h2h, WT3, xl8, NN);
  agg_kernel<4, 2, false, true, 10, 512><<<NN / 8, 512, 0, stream>>>(
      h2h, (const char*)xl8, att3, b3, csr, rowstart, perm, out, nullptr);
}

// Round 24
// 270.309 us; speedup vs baseline: 1.2420x; 1.0289x over previous
//
#include <hip/hip_runtime.h>
#include <math.h>

#define NN 20000
#define NE 160000
#define DH 128

typedef _Float16 f16;
typedef f16 f16x2 __attribute__((ext_vector_type(2)));
typedef f16 f16x4 __attribute__((ext_vector_type(4)));
typedef f16 f16x8 __attribute__((ext_vector_type(8)));
typedef float f32x4 __attribute__((ext_vector_type(4)));
typedef unsigned int uint32;
typedef unsigned char u8;

// ---------------- prep: fused x->f16 convert + degree count + weight transpose ----
#define NB_CONV 2500
__global__ __launch_bounds__(256) void prep_kernel(
    const float* __restrict__ X, f16* __restrict__ XH, int n4,
    const int* __restrict__ edst, int* __restrict__ deg, int ne,
    const float* __restrict__ W0, const float* __restrict__ W1,
    const float* __restrict__ W2, const float* __restrict__ W3,
    const float* __restrict__ W4, const float* __restrict__ W5,
    f16* O0, f16* O1, f16* O2, f16* O3, f16* O4, f16* O5) {
  int bid = blockIdx.x;
  if (bid < NB_CONV) {
    int i = bid * 256 + threadIdx.x;
    if (i < n4) {
      float4 v = *(const float4*)(X + (size_t)i * 4);
      f16x4 o = {(f16)v.x, (f16)v.y, (f16)v.z, (f16)v.w};
      *(f16x4*)(XH + (size_t)i * 4) = o;
    }
    if (i < ne) atomicAdd(&deg[edst[i]], 1);
    return;
  }
  int r = bid - NB_CONV;
  int z = r >> 7, sub = r & 127;
  const float* W; f16* O; int HC;
  switch (z) {
    case 0: W = W0; O = O0; HC = 1024; break;
    case 1: W = W1; O = O1; HC = 1024; break;
    case 2: W = W2; O = O2; HC = 1024; break;
    case 3: W = W3; O = O3; HC = 1024; break;
    case 4: W = W4; O = O4; HC = 512; break;
    default: W = W5; O = O5; HC = 512; break;
  }
  int c0 = (sub & 31) * 32;
  if (c0 >= HC) return;
  int k0 = (sub >> 5) * 32;
  __shared__ float t[32][33];
  int tx = threadIdx.x & 31, ty = threadIdx.x >> 5;
#pragma unroll
  for (int j = 0; j < 4; j++) {
    int k = k0 + ty + j * 8;
    t[ty + j * 8][tx] = W[(size_t)k * HC + c0 + tx];
  }
  __syncthreads();
#pragma unroll
  for (int j = 0; j < 4; j++) {
    int c = c0 + ty + j * 8;
    O[(size_t)c * 128 + k0 + tx] = (f16)t[tx][ty + j * 8];
  }
}

// ---------------- CSR build (2-phase) ----------------
__global__ __launch_bounds__(1024) void csr_p1(const int* __restrict__ deg,
                                               int* __restrict__ rowstart,
                                               int* __restrict__ bsum,
                                               int* __restrict__ ghist, int n) {
  __shared__ int wsum[16];
  __shared__ int lhist[64];
  const int tid = threadIdx.x;
  const int lane = tid & 63, w = tid >> 6;
  if (tid < 64) lhist[tid] = 0;
  __syncthreads();
  int i = blockIdx.x * 1024 + tid;
  int d = (i < n) ? deg[i] : 0;
  if (i < n) atomicAdd(&lhist[d < 63 ? d : 63], 1);
  int v = d;
#pragma unroll
  for (int off = 1; off < 64; off <<= 1) {
    int u = __shfl_up(v, off, 64);
    if (lane >= off) v += u;
  }
  if (lane == 63) wsum[w] = v;
  __syncthreads();
  if (w == 0) {
    int t = (lane < 16) ? wsum[lane] : 0;
#pragma unroll
    for (int off = 1; off < 16; off <<= 1) {
      int u = __shfl_up(t, off, 64);
      if (lane >= off) t += u;
    }
    if (lane < 16) wsum[lane] = t;
  }
  __syncthreads();
  int add = (w > 0 ? wsum[w - 1] : 0);
  if (i < n) rowstart[i + 1] = v + add;
  if (tid == 0) bsum[blockIdx.x] = wsum[15];
  if (tid < 64) ghist[blockIdx.x * 64 + tid] = lhist[tid];
}

__global__ __launch_bounds__(1024) void csr_p3(const int* __restrict__ deg,
                                               int* __restrict__ rowstart,
                                               const int* __restrict__ bsum,
                                               const int* __restrict__ ghist,
                                               int* __restrict__ perm, int n, int nb) {
  __shared__ int lcur[64];
  __shared__ int base[64];
  __shared__ int radd_s;
  const int tid = threadIdx.x;
  if (tid < 64) {
    lcur[tid] = 0;
    int pre = 0, tot = 0;
    for (int b = 0; b < nb; b++) {
      int v = ghist[b * 64 + tid];
      pre += (b < (int)blockIdx.x) ? v : 0;
      tot += v;
    }
    int incl = tot;
#pragma unroll
    for (int off = 1; off < 64; off <<= 1) {
      int u = __shfl_up(incl, off, 64);
      if (tid >= off) incl += u;
    }
    base[tid] = (n - incl) + pre;
  }
  if (tid == 0) {
    int r = 0;
    for (int b = 0; b < (int)blockIdx.x; b++) r += bsum[b];
    radd_s = r;
  }
  __syncthreads();
  int i = blockIdx.x * 1024 + tid;
  if (i < n) {
    rowstart[i + 1] += radd_s;
    int d = deg[i];
    int b = d < 63 ? d : 63;
    int pos = atomicAdd(&lcur[b], 1);
    perm[base[b] + pos] = i;
  }
  if (blockIdx.x == 0 && tid == 0) rowstart[0] = 0;
}

__global__ void scatter_kernel(const int* __restrict__ src, const int* __restrict__ dstp,
                               const int* __restrict__ rowstart, int* __restrict__ cursor,
                               int* __restrict__ csr, int n) {
  int i = blockIdx.x * blockDim.x + threadIdx.x;
  if (i < n) {
    int d = dstp[i];
    int pos = atomicAdd(&cursor[d], 1);
    csr[rowstart[d] + pos] = src[i];
  }
}

// sort body: one 16-lane subgroup per row; 16-element bitonic network.
__device__ __forceinline__ void sort_body(const int* __restrict__ rowstart,
                                          int* __restrict__ csr,
                                          const int* __restrict__ perm,
                                          int idx, int n) {
  int sub = idx >> 4;
  int u = idx & 15;
  if (sub >= n) return;
  int i = perm[sub];
  int a = rowstart[i], b = rowstart[i + 1];
  int d = b - a;
  if (d <= 1) return;
  if (d <= 16) {
    int v = (u < d) ? csr[a + u] : 0x7FFFFFFF;
#pragma unroll
    for (int k = 2; k <= 16; k <<= 1) {
#pragma unroll
      for (int j = 16; j > 0; j >>= 1) {
        if (j > (k >> 1)) continue;
        int o = __shfl_xor(v, j, 64);
        bool takeMin = (((u & k) == 0) == ((u & j) == 0));
        v = takeMin ? (v < o ? v : o) : (v > o ? v : o);
      }
    }
    if (u < d) csr[a + u] = v;
  } else if (u == 0) {
    for (int j = a + 1; j < b; j++) {
      int v = csr[j];
      int k = j - 1;
      while (k >= a && csr[k] > v) { csr[k + 1] = csr[k]; k--; }
      csr[k + 1] = v;
    }
  }
}

// ---------------- f16 MFMA GEMM body, whole-row fp8 output ----------------
// R17-R22 GEMM ladder: one-pass fragment-direct = best; structure FROZEN.
template <int YB>
__device__ __forceinline__ void gemm_f8_body(const f16* __restrict__ A,
                                             const f16* __restrict__ BT,
                                             u8* __restrict__ C8, int M, int bid,
                                             f16 (*ct)[144]) {
  const int ROWB = YB * 128;
  const int nx = (M + 127) / 128;
  const int chunk = nx * YB / 8;
  const int p = (bid % 8) * chunk + bid / 8;
  const int bx = p / YB, by = p % YB;

  const int w = threadIdx.x >> 6, lane = threadIdx.x & 63;
  const int wm = w >> 1, wn = w & 1;
  const int row0 = bx * 128 + wm * 64;
  const int col0 = by * 128 + wn * 64;
  const int lr = lane & 15, lk = (lane >> 4) * 8;

  f32x4 acc[4][4] = {};
  const f16* Arow[4];
  const f16* Brow[4];
#pragma unroll
  for (int m = 0; m < 4; m++) {
    int r = row0 + m * 16 + lr;
    r = r < M ? r : M - 1;
    Arow[m] = A + (size_t)r * 128 + lk;
  }
#pragma unroll
  for (int n = 0; n < 4; n++) {
    int c = col0 + n * 16 + lr;
    Brow[n] = BT + (size_t)c * 128 + lk;
  }
  f16x8 a[4][4], b[4][4];  // hoisted [ks][m]/[ks][n]
#pragma unroll
  for (int ks = 0; ks < 4; ks++) {
#pragma unroll
    for (int m = 0; m < 4; m++) a[ks][m] = *(const f16x8*)(Arow[m] + ks * 32);
#pragma unroll
    for (int n = 0; n < 4; n++) b[ks][n] = *(const f16x8*)(Brow[n] + ks * 32);
  }
#pragma unroll
  for (int ks = 0; ks < 4; ks++)
#pragma unroll
    for (int m = 0; m < 4; m++)
#pragma unroll
      for (int n = 0; n < 4; n++)
        acc[m][n] = __builtin_amdgcn_mfma_f32_16x16x32_f16(a[ks][m], b[ks][n],
                                                           acc[m][n], 0, 0, 0);
  const int lrow = wm * 64, lcol = wn * 64;
#pragma unroll
  for (int m = 0; m < 4; m++) {
    int rbase = lrow + m * 16 + (lane >> 4) * 4;
#pragma unroll
    for (int r = 0; r < 4; r++) {
#pragma unroll
      for (int n = 0; n < 4; n++) {
        ct[rbase + r][lcol + n * 16 + lr] = (f16)acc[m][n][r];
      }
    }
  }
  __syncthreads();
  const int t = threadIdx.x;
  const int cidx = (t & 15) * 8;
  const int rowblk = bx * 128, colblk = by * 128;
#pragma unroll
  for (int rr = (t >> 4); rr < 128; rr += 16) {
    int gr = rowblk + rr;
    if (gr < M) {
      f16x8 v = *(const f16x8*)(&ct[rr][cidx]);
      int lo = __builtin_amdgcn_cvt_pk_fp8_f32((float)v[0], (float)v[1], 0, false);
      lo = __builtin_amdgcn_cvt_pk_fp8_f32((float)v[2], (float)v[3], lo, true);
      int hi = __builtin_amdgcn_cvt_pk_fp8_f32((float)v[4], (float)v[5], 0, false);
      hi = __builtin_amdgcn_cvt_pk_fp8_f32((float)v[6], (float)v[7], hi, true);
      uint2 o;
      o.x = (uint32)lo;
      o.y = (uint32)hi;
      *(uint2*)(C8 + (size_t)gr * ROWB + colblk + cidx) = o;
    }
  }
}

template <int YB>
__global__ __launch_bounds__(256) void gemm_f8(const f16* __restrict__ A,
                                               const f16* __restrict__ BT,
                                               u8* __restrict__ C8, int M) {
  __shared__ f16 ct[128][144];
  gemm_f8_body<YB>(A, BT, C8, M, blockIdx.x, ct);
}

// fused: SORT BLOCKS FIRST (R23 lesson: appending sort after 2512 gemm blocks
// serialized the divergent sort tail AFTER the gemm -> 77us. Sort-first lets
// the short/divergent sort work run concurrently under the gemm stream.)
template <int YB>
__global__ __launch_bounds__(256) void gemm_sort_kernel(
    const f16* __restrict__ A, const f16* __restrict__ BT, u8* __restrict__ C8,
    int M, int nsort, const int* __restrict__ rowstart, int* __restrict__ csr,
    const int* __restrict__ perm, int n) {
  __shared__ f16 ct[128][144];
  int bid = blockIdx.x;
  if (bid < nsort) {
    int idx = bid * 256 + threadIdx.x;
    sort_body(rowstart, csr, perm, idx, n);
  } else {
    gemm_f8_body<YB>(A, BT, C8, M, bid - nsort, ct);
  }
}

// ---------------- fused GATv2 aggregation ----------------
// NOTE (R14): persistent grid-stride agg REGRESSED; keep 1-shot blocks.
// NOTE (R11): 8-deep masked merge REGRESSED; keep 4-deep + scalar tail.
struct LV { f16x2 v[4]; };

// fp8-e4m3 gather: 8 bytes -> 8 f16 via HW cvt (exact embeddings).
__device__ __forceinline__ LV load8_f8(const char* __restrict__ base, uint32 off) {
  uint2 w = *(const uint2*)(base + off);
  auto a = __builtin_amdgcn_cvt_pk_f32_fp8((int)w.x, false);
  auto b = __builtin_amdgcn_cvt_pk_f32_fp8((int)w.x, true);
  auto c = __builtin_amdgcn_cvt_pk_f32_fp8((int)w.y, false);
  auto d = __builtin_amdgcn_cvt_pk_f32_fp8((int)w.y, true);
  LV o;
  o.v[0] = __builtin_bit_cast(f16x2, __builtin_amdgcn_cvt_pkrtz(a[0], a[1]));
  o.v[1] = __builtin_bit_cast(f16x2, __builtin_amdgcn_cvt_pkrtz(b[0], b[1]));
  o.v[2] = __builtin_bit_cast(f16x2, __builtin_amdgcn_cvt_pkrtz(c[0], c[1]));
  o.v[3] = __builtin_bit_cast(f16x2, __builtin_amdgcn_cvt_pkrtz(d[0], d[1]));
  return o;
}

__device__ __forceinline__ f16x2 leaky2(f16x2 z) {
  f16x2 zs = z * (f16)0.2f;
  return __builtin_elementwise_max(z, zs);
}

__device__ __forceinline__ float edot(const LV& x, const f16x2* xr2, const f16x2* att2) {
  float ea = 0.f, eb = 0.f;
  ea = __builtin_amdgcn_fdot2(leaky2(x.v[0] + xr2[0]), att2[0], ea, false);
  eb = __builtin_amdgcn_fdot2(leaky2(x.v[1] + xr2[1]), att2[1], eb, false);
  ea = __builtin_amdgcn_fdot2(leaky2(x.v[2] + xr2[2]), att2[2], ea, false);
  eb = __builtin_amdgcn_fdot2(leaky2(x.v[3] + xr2[3]), att2[3], eb, false);
  return ea + eb;
}

template <int PAT>
__device__ __forceinline__ float swz(float x) {
  return __int_as_float(__builtin_amdgcn_ds_swizzle(__float_as_int(x), PAT));
}

__device__ __forceinline__ void red16x4(float& a, float& b, float& c, float& d) {
  a += swz<0x041F>(a); b += swz<0x041F>(b); c += swz<0x041F>(c); d += swz<0x041F>(d);
  a += swz<0x081F>(a); b += swz<0x081F>(b); c += swz<0x081F>(c); d += swz<0x081F>(d);
  a += swz<0x101F>(a); b += swz<0x101F>(b); c += swz<0x101F>(c); d += swz<0x101F>(d);
  a += swz<0x201F>(a); b += swz<0x201F>(b); c += swz<0x201F>(c); d += swz<0x201F>(d);
}
__device__ __forceinline__ float red16(float a) {
  a += swz<0x041F>(a);
  a += swz<0x081F>(a);
  a += swz<0x101F>(a);
  a += swz<0x201F>(a);
  return a;
}

// H heads; DG dst-groups/block; LGROW: log2 fp8 row stride; XROFF: xr byte off.
template <int H, int DG, bool RELU, bool WF32, int LGROW, int XROFF>
__global__ __launch_bounds__(H * DG * 64) void agg_kernel(
    const f16* __restrict__ h_in, const char* __restrict__ xp,
    const float* __restrict__ att, const float* __restrict__ bias,
    const int* __restrict__ csr, const int* __restrict__ rowstart,
    const int* __restrict__ perm,
    float* __restrict__ h_out, f16* __restrict__ hh) {
  __shared__ float headout[H][4 * DG][DH];
  __shared__ int nodes[4 * DG];
  const int wv = threadIdx.x >> 6;
  const int h = wv & (H - 1);
  const int dg = wv / H;
  const int lane = threadIdx.x & 63;
  const int g = lane >> 4, u = lane & 15;
  const int c0 = u * 8;
  if (threadIdx.x < 4 * DG) nodes[threadIdx.x] = perm[blockIdx.x * 4 * DG + threadIdx.x];
  const int dst = perm[blockIdx.x * 4 * DG + dg * 4 + g];
  const uint32 loff = (uint32)(h * DH + c0);  // fp8: 1 byte/elem

  f16x2 att2[4], xr2[4];
  {
    const float* ap = att + h * DH + c0;
    float a0[8];
    *(float4*)a0 = *(const float4*)ap;
    *(float4*)(a0 + 4) = *(const float4*)(ap + 4);
#pragma unroll
    for (int q = 0; q < 4; q++) att2[q] = f16x2{(f16)a0[2 * q], (f16)a0[2 * q + 1]};
    LV xrv = load8_f8(xp, ((uint32)dst << LGROW) + XROFF + loff);
#pragma unroll
    for (int q = 0; q < 4; q++) xr2[q] = xrv.v[q];
  }

  const int js = rowstart[dst], je = rowstart[dst + 1];

  // self loop seed
  float m, s;
  f16x2 acc[4];
  {
    LV xv = load8_f8(xp, ((uint32)dst << LGROW) + loff);
    m = red16(edot(xv, xr2, att2));
    s = 1.f;
#pragma unroll
    for (int q = 0; q < 4; q++) acc[q] = xv.v[q];
  }

  // 4-deep prefetch over CSR row (indices clamped to je-1)
  LV pf0, pf1, pf2, pf3;
  {
    int ja = js < je ? js : je - 1;
    int jb = js + 1 < je ? js + 1 : je - 1;
    int jc = js + 2 < je ? js + 2 : je - 1;
    int jd = js + 3 < je ? js + 3 : je - 1;
    if (js < je) {
      pf0 = load8_f8(xp, ((uint32)csr[ja] << LGROW) + loff);
      pf1 = load8_f8(xp, ((uint32)csr[jb] << LGROW) + loff);
      pf2 = load8_f8(xp, ((uint32)csr[jc] << LGROW) + loff);
      pf3 = load8_f8(xp, ((uint32)csr[jd] << LGROW) + loff);
    }
  }

  int j = js;
  for (; j + 3 < je; j += 4) {
    LV cv0 = pf0, cv1 = pf1, cv2 = pf2, cv3 = pf3;
    int ja = j + 4 < je ? j + 4 : je - 1;
    int jb = j + 5 < je ? j + 5 : je - 1;
    int jc = j + 6 < je ? j + 6 : je - 1;
    int jd = j + 7 < je ? j + 7 : je - 1;
    pf0 = load8_f8(xp, ((uint32)csr[ja] << LGROW) + loff);
    pf1 = load8_f8(xp, ((uint32)csr[jb] << LGROW) + loff);
    pf2 = load8_f8(xp, ((uint32)csr[jc] << LGROW) + loff);
    pf3 = load8_f8(xp, ((uint32)csr[jd] << LGROW) + loff);

    float e0 = edot(cv0, xr2, att2);
    float e1 = edot(cv1, xr2, att2);
    float e2 = edot(cv2, xr2, att2);
    float e3 = edot(cv3, xr2, att2);
    red16x4(e0, e1, e2, e3);

    float mn = fmaxf(fmaxf(fmaxf(m, e0), fmaxf(e1, e2)), e3);
    float a = __expf(m - mn);
    float p0 = __expf(e0 - mn);
    float p1 = __expf(e1 - mn);
    float p2 = __expf(e2 - mn);
    float p3 = __expf(e3 - mn);
    s = s * a + ((p0 + p1) + (p2 + p3));
    f16 ah = (f16)a, g0 = (f16)p0, g1 = (f16)p1, g2 = (f16)p2, g3 = (f16)p3;
    f16x2 a2 = {ah, ah}, q0 = {g0, g0}, q1 = {g1, g1}, q2 = {g2, g2}, q3 = {g3, g3};
#pragma unroll
    for (int q = 0; q < 4; q++) {
      f16x2 t = acc[q] * a2;
      t = cv0.v[q] * q0 + t;
      t = cv1.v[q] * q1 + t;
      t = cv2.v[q] * q2 + t;
      t = cv3.v[q] * q3 + t;
      acc[q] = t;
    }
    m = mn;
  }
  // tail: consume remaining prefetched edges one at a time
  for (int t = 0; j < je; j++, t++) {
    LV cv = (t == 0) ? pf0 : (t == 1) ? pf1 : pf2;
    float e = red16(edot(cv, xr2, att2));
    float mn = fmaxf(m, e);
    float a = __expf(m - mn);
    float p = __expf(e - mn);
    s = s * a + p;
    f16 ah = (f16)a, gh = (f16)p;
    f16x2 a2 = {ah, ah}, p2 = {gh, gh};
#pragma unroll
    for (int q = 0; q < 4; q++) acc[q] = acc[q] * a2 + cv.v[q] * p2;
    m = mn;
  }

  float inv = 1.f / s;
#pragma unroll
  for (int q = 0; q < 4; q++) {
    headout[h][dg * 4 + g][c0 + 2 * q] = (float)acc[q][0] * inv;
    headout[h][dg * 4 + g][c0 + 2 * q + 1] = (float)acc[q][1] * inv;
  }
  __syncthreads();
  for (int t = threadIdx.x; t < 4 * DG * DH; t += H * DG * 64) {
    int d = t >> 7, c = t & 127;
    float sum = 0.f;
#pragma unroll
    for (int q = 0; q < H; q++) sum += headout[q][d][c];
    float r = sum * (1.f / H) + bias[c];
    if (RELU) r = fmaxf(r, 0.f);
    int node = nodes[d];
    float o = r + (float)h_in[(size_t)node * DH + c];
    if (WF32) h_out[(size_t)node * DH + c] = o;
    else hh[(size_t)node * DH + c] = (f16)o;
  }
}

extern "C" void kernel_launch(void* const* d_in, const int* in_sizes, int n_in,
                              void* d_out, int out_size, void* d_ws, size_t ws_size,
                              hipStream_t stream) {
  const float* x = (const float*)d_in[0];
  const int* ei = (const int*)d_in[1];
  const float* Wl1 = (const float*)d_in[2];
  const float* Wr1 = (const float*)d_in[3];
  const float* att1 = (const float*)d_in[4];
  const float* b1 = (const float*)d_in[5];
  const float* Wl2 = (const float*)d_in[6];
  const float* Wr2 = (const float*)d_in[7];
  const float* att2 = (const float*)d_in[8];
  const float* b2 = (const float*)d_in[9];
  const float* Wl3 = (const float*)d_in[10];
  const float* Wr3 = (const float*)d_in[11];
  const float* att3 = (const float*)d_in[12];
  const float* b3 = (const float*)d_in[13];
  float* out = (float*)d_out;

  char* p = (char*)d_ws;
  u8* xl8  = (u8*)p;  p += (size_t)NN * 2048;   // fp8 xl|xr (all layers)
  f16* xh  = (f16*)p; p += (size_t)NN * DH * 2;
  f16* h1h = (f16*)p; p += (size_t)NN * DH * 2;
  f16* h2h = (f16*)p; p += (size_t)NN * DH * 2;
  f16* WT1 = (f16*)p; p += (size_t)2048 * 128 * 2;
  f16* WT2 = (f16*)p; p += (size_t)2048 * 128 * 2;
  f16* WT3 = (f16*)p; p += (size_t)1024 * 128 * 2;
  int* deg      = (int*)p; p += (size_t)NN * 4;
  int* cursor   = (int*)p; p += (size_t)NN * 4;
  int* rowstart = (int*)p; p += (size_t)(NN + 1) * 4;
  int* perm     = (int*)p; p += (size_t)NN * 4;
  int* bsum     = (int*)p; p += (size_t)32 * 4;
  int* ghist    = (int*)p; p += (size_t)20 * 64 * 4;
  int* csr      = (int*)p;

  const int* esrc = ei;
  const int* edst = ei + NE;

  const int nbc = (NN + 1023) / 1024;  // 20 CSR-build blocks

  hipMemsetAsync(deg, 0, sizeof(int) * 2 * NN, stream);  // deg + cursor
  prep_kernel<<<NB_CONV + 6 * 128, 256, 0, stream>>>(
      x, xh, NN * DH / 4, edst, deg, NE,
      Wl1, Wr1, Wl2, Wr2, Wl3, Wr3,
      WT1, WT1 + (size_t)1024 * 128, WT2, WT2 + (size_t)1024 * 128,
      WT3, WT3 + (size_t)512 * 128);
  csr_p1<<<nbc, 1024, 0, stream>>>(deg, rowstart, bsum, ghist, NN);
  csr_p3<<<nbc, 1024, 0, stream>>>(deg, rowstart, bsum, ghist, perm, NN, nbc);
  scatter_kernel<<<(NE + 255) / 256, 256, 0, stream>>>(esrc, edst, rowstart, cursor, csr, NE);

  const int nx = (NN + 127) / 128;  // 157
  const int ngemm1 = nx * 16;       // 2512
  const int nsort = (NN * 16 + 255) / 256;  // 1250

  // layer 1: [sort || gemm1] — sort blocks FIRST so they overlap the gemm stream
  gemm_sort_kernel<16><<<nsort + ngemm1, 256, 0, stream>>>(
      xh, WT1, xl8, NN, nsort, rowstart, csr, perm, NN);
  agg_kernel<8, 1, true, false, 11, 1024><<<NN / 4, 512, 0, stream>>>(
      xh, (const char*)xl8, att1, b1, csr, rowstart, perm, nullptr, h1h);
  // layer 2
  gemm_f8<16><<<nx * 16, 256, 0, stream>>>(h1h, WT2, xl8, NN);
  agg_kernel<8, 1, true, false, 11, 1024><<<NN / 4, 512, 0, stream>>>(
      h1h, (const char*)xl8, att2, b2, csr, rowstart, perm, nullptr, h2h);
  // layer 3: fp8 rows 1024 B (xl 0-511 | xr 512-1023), f32 output + residual
  gemm_f8<8><<<nx * 8, 256, 0, stream>>>(h2h, WT3, xl8, NN);
  agg_kernel<4, 2, false, true, 10, 512><<<NN / 8, 512, 0, stream>>>(
      h2h, (const char*)xl8, att3, b3, csr, rowstart, perm, out, nullptr);
}

// Round 25
// 253.540 us; speedup vs baseline: 1.3242x; 1.0661x over previous
//
#include <hip/hip_runtime.h>
#include <math.h>

#define NN 20000
#define NE 160000
#define DH 128
#define NWR 4096  // first NWR perm rows sorted wave-per-row (covers all deg>16)

typedef _Float16 f16;
typedef f16 f16x2 __attribute__((ext_vector_type(2)));
typedef f16 f16x4 __attribute__((ext_vector_type(4)));
typedef f16 f16x8 __attribute__((ext_vector_type(8)));
typedef float f32x4 __attribute__((ext_vector_type(4)));
typedef unsigned int uint32;
typedef unsigned char u8;

// ---------------- prep: fused x->f16 convert + degree count + weight transpose ----
#define NB_CONV 2500
__global__ __launch_bounds__(256) void prep_kernel(
    const float* __restrict__ X, f16* __restrict__ XH, int n4,
    const int* __restrict__ edst, int* __restrict__ deg, int ne,
    const float* __restrict__ W0, const float* __restrict__ W1,
    const float* __restrict__ W2, const float* __restrict__ W3,
    const float* __restrict__ W4, const float* __restrict__ W5,
    f16* O0, f16* O1, f16* O2, f16* O3, f16* O4, f16* O5) {
  int bid = blockIdx.x;
  if (bid < NB_CONV) {
    int i = bid * 256 + threadIdx.x;
    if (i < n4) {
      float4 v = *(const float4*)(X + (size_t)i * 4);
      f16x4 o = {(f16)v.x, (f16)v.y, (f16)v.z, (f16)v.w};
      *(f16x4*)(XH + (size_t)i * 4) = o;
    }
    if (i < ne) atomicAdd(&deg[edst[i]], 1);
    return;
  }
  int r = bid - NB_CONV;
  int z = r >> 7, sub = r & 127;
  const float* W; f16* O; int HC;
  switch (z) {
    case 0: W = W0; O = O0; HC = 1024; break;
    case 1: W = W1; O = O1; HC = 1024; break;
    case 2: W = W2; O = O2; HC = 1024; break;
    case 3: W = W3; O = O3; HC = 1024; break;
    case 4: W = W4; O = O4; HC = 512; break;
    default: W = W5; O = O5; HC = 512; break;
  }
  int c0 = (sub & 31) * 32;
  if (c0 >= HC) return;
  int k0 = (sub >> 5) * 32;
  __shared__ float t[32][33];
  int tx = threadIdx.x & 31, ty = threadIdx.x >> 5;
#pragma unroll
  for (int j = 0; j < 4; j++) {
    int k = k0 + ty + j * 8;
    t[ty + j * 8][tx] = W[(size_t)k * HC + c0 + tx];
  }
  __syncthreads();
#pragma unroll
  for (int j = 0; j < 4; j++) {
    int c = c0 + ty + j * 8;
    O[(size_t)c * 128 + k0 + tx] = (f16)t[tx][ty + j * 8];
  }
}

// ---------------- CSR build (2-phase) ----------------
__global__ __launch_bounds__(1024) void csr_p1(const int* __restrict__ deg,
                                               int* __restrict__ rowstart,
                                               int* __restrict__ bsum,
                                               int* __restrict__ ghist, int n) {
  __shared__ int wsum[16];
  __shared__ int lhist[64];
  const int tid = threadIdx.x;
  const int lane = tid & 63, w = tid >> 6;
  if (tid < 64) lhist[tid] = 0;
  __syncthreads();
  int i = blockIdx.x * 1024 + tid;
  int d = (i < n) ? deg[i] : 0;
  if (i < n) atomicAdd(&lhist[d < 63 ? d : 63], 1);
  int v = d;
#pragma unroll
  for (int off = 1; off < 64; off <<= 1) {
    int u = __shfl_up(v, off, 64);
    if (lane >= off) v += u;
  }
  if (lane == 63) wsum[w] = v;
  __syncthreads();
  if (w == 0) {
    int t = (lane < 16) ? wsum[lane] : 0;
#pragma unroll
    for (int off = 1; off < 16; off <<= 1) {
      int u = __shfl_up(t, off, 64);
      if (lane >= off) t += u;
    }
    if (lane < 16) wsum[lane] = t;
  }
  __syncthreads();
  int add = (w > 0 ? wsum[w - 1] : 0);
  if (i < n) rowstart[i + 1] = v + add;
  if (tid == 0) bsum[blockIdx.x] = wsum[15];
  if (tid < 64) ghist[blockIdx.x * 64 + tid] = lhist[tid];
}

__global__ __launch_bounds__(1024) void csr_p3(const int* __restrict__ deg,
                                               int* __restrict__ rowstart,
                                               const int* __restrict__ bsum,
                                               const int* __restrict__ ghist,
                                               int* __restrict__ perm, int n, int nb) {
  __shared__ int lcur[64];
  __shared__ int base[64];
  __shared__ int radd_s;
  const int tid = threadIdx.x;
  if (tid < 64) {
    lcur[tid] = 0;
    int pre = 0, tot = 0;
    for (int b = 0; b < nb; b++) {
      int v = ghist[b * 64 + tid];
      pre += (b < (int)blockIdx.x) ? v : 0;
      tot += v;
    }
    int incl = tot;
#pragma unroll
    for (int off = 1; off < 64; off <<= 1) {
      int u = __shfl_up(incl, off, 64);
      if (tid >= off) incl += u;
    }
    base[tid] = (n - incl) + pre;
  }
  if (tid == 0) {
    int r = 0;
    for (int b = 0; b < (int)blockIdx.x; b++) r += bsum[b];
    radd_s = r;
  }
  __syncthreads();
  int i = blockIdx.x * 1024 + tid;
  if (i < n) {
    rowstart[i + 1] += radd_s;
    int d = deg[i];
    int b = d < 63 ? d : 63;
    int pos = atomicAdd(&lcur[b], 1);
    perm[base[b] + pos] = i;
  }
  if (blockIdx.x == 0 && tid == 0) rowstart[0] = 0;
}

__global__ void scatter_kernel(const int* __restrict__ src, const int* __restrict__ dstp,
                               const int* __restrict__ rowstart, int* __restrict__ cursor,
                               int* __restrict__ csr, int n) {
  int i = blockIdx.x * blockDim.x + threadIdx.x;
  if (i < n) {
    int d = dstp[i];
    int pos = atomicAdd(&cursor[d], 1);
    csr[rowstart[d] + pos] = src[i];
  }
}

// ---------------- sort bodies ----------------
// wave-per-row: 64-element bitonic over the full wave (deg<=64; serial
// fallback for larger, never triggered at Poisson(8)). R24 lesson: the
// deg>16 serial insertion sort through global memory was ~50us of serial
// critical path (300 dependent L2 accesses x ~200cy) -- dominated the
// fused dispatch.
__device__ __forceinline__ void sort_row_wave(const int* __restrict__ rowstart,
                                              int* __restrict__ csr, int i) {
  const int lane = threadIdx.x & 63;
  int a = rowstart[i], b = rowstart[i + 1];
  int d = b - a;
  if (d <= 1) return;
  if (d <= 64) {
    int v = (lane < d) ? csr[a + lane] : 0x7FFFFFFF;
#pragma unroll
    for (int k = 2; k <= 64; k <<= 1) {
#pragma unroll
      for (int j = 32; j > 0; j >>= 1) {
        if (j > (k >> 1)) continue;
        int o = __shfl_xor(v, j, 64);
        bool takeMin = (((lane & k) == 0) == ((lane & j) == 0));
        v = takeMin ? (v < o ? v : o) : (v > o ? v : o);
      }
    }
    if (lane < d) csr[a + lane] = v;
  } else if (lane == 0) {
    for (int j = a + 1; j < b; j++) {
      int v = csr[j];
      int k = j - 1;
      while (k >= a && csr[k] > v) { csr[k + 1] = csr[k]; k--; }
      csr[k + 1] = v;
    }
  }
}

// subgroup-per-row: 16-element bitonic (rows beyond NWR all have deg<=16;
// serial fallback kept for safety).
__device__ __forceinline__ void sort_body(const int* __restrict__ rowstart,
                                          int* __restrict__ csr,
                                          const int* __restrict__ perm,
                                          int idx, int n) {
  int sub = idx >> 4;
  int u = idx & 15;
  if (sub >= n) return;
  int i = perm[sub];
  int a = rowstart[i], b = rowstart[i + 1];
  int d = b - a;
  if (d <= 1) return;
  if (d <= 16) {
    int v = (u < d) ? csr[a + u] : 0x7FFFFFFF;
#pragma unroll
    for (int k = 2; k <= 16; k <<= 1) {
#pragma unroll
      for (int j = 16; j > 0; j >>= 1) {
        if (j > (k >> 1)) continue;
        int o = __shfl_xor(v, j, 64);
        bool takeMin = (((u & k) == 0) == ((u & j) == 0));
        v = takeMin ? (v < o ? v : o) : (v > o ? v : o);
      }
    }
    if (u < d) csr[a + u] = v;
  } else if (u == 0) {
    for (int j = a + 1; j < b; j++) {
      int v = csr[j];
      int k = j - 1;
      while (k >= a && csr[k] > v) { csr[k + 1] = csr[k]; k--; }
      csr[k + 1] = v;
    }
  }
}

// ---------------- f16 MFMA GEMM body, whole-row fp8 output ----------------
// R17-R22 GEMM ladder: one-pass fragment-direct = best; structure FROZEN.
template <int YB>
__device__ __forceinline__ void gemm_f8_body(const f16* __restrict__ A,
                                             const f16* __restrict__ BT,
                                             u8* __restrict__ C8, int M, int bid,
                                             f16 (*ct)[144]) {
  const int ROWB = YB * 128;
  const int nx = (M + 127) / 128;
  const int chunk = nx * YB / 8;
  const int p = (bid % 8) * chunk + bid / 8;
  const int bx = p / YB, by = p % YB;

  const int w = threadIdx.x >> 6, lane = threadIdx.x & 63;
  const int wm = w >> 1, wn = w & 1;
  const int row0 = bx * 128 + wm * 64;
  const int col0 = by * 128 + wn * 64;
  const int lr = lane & 15, lk = (lane >> 4) * 8;

  f32x4 acc[4][4] = {};
  const f16* Arow[4];
  const f16* Brow[4];
#pragma unroll
  for (int m = 0; m < 4; m++) {
    int r = row0 + m * 16 + lr;
    r = r < M ? r : M - 1;
    Arow[m] = A + (size_t)r * 128 + lk;
  }
#pragma unroll
  for (int n = 0; n < 4; n++) {
    int c = col0 + n * 16 + lr;
    Brow[n] = BT + (size_t)c * 128 + lk;
  }
  f16x8 a[4][4], b[4][4];  // hoisted [ks][m]/[ks][n]
#pragma unroll
  for (int ks = 0; ks < 4; ks++) {
#pragma unroll
    for (int m = 0; m < 4; m++) a[ks][m] = *(const f16x8*)(Arow[m] + ks * 32);
#pragma unroll
    for (int n = 0; n < 4; n++) b[ks][n] = *(const f16x8*)(Brow[n] + ks * 32);
  }
#pragma unroll
  for (int ks = 0; ks < 4; ks++)
#pragma unroll
    for (int m = 0; m < 4; m++)
#pragma unroll
      for (int n = 0; n < 4; n++)
        acc[m][n] = __builtin_amdgcn_mfma_f32_16x16x32_f16(a[ks][m], b[ks][n],
                                                           acc[m][n], 0, 0, 0);
  const int lrow = wm * 64, lcol = wn * 64;
#pragma unroll
  for (int m = 0; m < 4; m++) {
    int rbase = lrow + m * 16 + (lane >> 4) * 4;
#pragma unroll
    for (int r = 0; r < 4; r++) {
#pragma unroll
      for (int n = 0; n < 4; n++) {
        ct[rbase + r][lcol + n * 16 + lr] = (f16)acc[m][n][r];
      }
    }
  }
  __syncthreads();
  const int t = threadIdx.x;
  const int cidx = (t & 15) * 8;
  const int rowblk = bx * 128, colblk = by * 128;
#pragma unroll
  for (int rr = (t >> 4); rr < 128; rr += 16) {
    int gr = rowblk + rr;
    if (gr < M) {
      f16x8 v = *(const f16x8*)(&ct[rr][cidx]);
      int lo = __builtin_amdgcn_cvt_pk_fp8_f32((float)v[0], (float)v[1], 0, false);
      lo = __builtin_amdgcn_cvt_pk_fp8_f32((float)v[2], (float)v[3], lo, true);
      int hi = __builtin_amdgcn_cvt_pk_fp8_f32((float)v[4], (float)v[5], 0, false);
      hi = __builtin_amdgcn_cvt_pk_fp8_f32((float)v[6], (float)v[7], hi, true);
      uint2 o;
      o.x = (uint32)lo;
      o.y = (uint32)hi;
      *(uint2*)(C8 + (size_t)gr * ROWB + colblk + cidx) = o;
    }
  }
}

template <int YB>
__global__ __launch_bounds__(256) void gemm_f8(const f16* __restrict__ A,
                                               const f16* __restrict__ BT,
                                               u8* __restrict__ C8, int M) {
  __shared__ f16 ct[128][144];
  gemm_f8_body<YB>(A, BT, C8, M, blockIdx.x, ct);
}

// fused: sort blocks FIRST (R23/R24 lessons). Layout:
//   [0, NWB): wave-per-row sort of perm[0..NWR) (heavy rows, 4 waves/block)
//   [NWB, NWB+nsub): subgroup-per-row sort of perm[NWR..n)
//   [NWB+nsub, ...): layer-1 GEMM
template <int YB>
__global__ __launch_bounds__(256) void gemm_sort_kernel(
    const f16* __restrict__ A, const f16* __restrict__ BT, u8* __restrict__ C8,
    int M, int nwb, int nsub, const int* __restrict__ rowstart,
    int* __restrict__ csr, const int* __restrict__ perm, int n) {
  __shared__ f16 ct[128][144];
  int bid = blockIdx.x;
  if (bid < nwb) {
    int row = bid * 4 + (threadIdx.x >> 6);
    if (row < NWR && row < n) sort_row_wave(rowstart, csr, perm[row]);
  } else if (bid < nwb + nsub) {
    int idx = (bid - nwb) * 256 + threadIdx.x;
    sort_body(rowstart, csr, perm + NWR, idx, n - NWR);
  } else {
    gemm_f8_body<YB>(A, BT, C8, M, bid - nwb - nsub, ct);
  }
}

// ---------------- fused GATv2 aggregation ----------------
// NOTE (R14): persistent grid-stride agg REGRESSED; keep 1-shot blocks.
// NOTE (R11): 8-deep masked merge REGRESSED; keep 4-deep + scalar tail.
struct LV { f16x2 v[4]; };

// fp8-e4m3 gather: 8 bytes -> 8 f16 via HW cvt (exact embeddings).
__device__ __forceinline__ LV load8_f8(const char* __restrict__ base, uint32 off) {
  uint2 w = *(const uint2*)(base + off);
  auto a = __builtin_amdgcn_cvt_pk_f32_fp8((int)w.x, false);
  auto b = __builtin_amdgcn_cvt_pk_f32_fp8((int)w.x, true);
  auto c = __builtin_amdgcn_cvt_pk_f32_fp8((int)w.y, false);
  auto d = __builtin_amdgcn_cvt_pk_f32_fp8((int)w.y, true);
  LV o;
  o.v[0] = __builtin_bit_cast(f16x2, __builtin_amdgcn_cvt_pkrtz(a[0], a[1]));
  o.v[1] = __builtin_bit_cast(f16x2, __builtin_amdgcn_cvt_pkrtz(b[0], b[1]));
  o.v[2] = __builtin_bit_cast(f16x2, __builtin_amdgcn_cvt_pkrtz(c[0], c[1]));
  o.v[3] = __builtin_bit_cast(f16x2, __builtin_amdgcn_cvt_pkrtz(d[0], d[1]));
  return o;
}

__device__ __forceinline__ f16x2 leaky2(f16x2 z) {
  f16x2 zs = z * (f16)0.2f;
  return __builtin_elementwise_max(z, zs);
}

__device__ __forceinline__ float edot(const LV& x, const f16x2* xr2, const f16x2* att2) {
  float ea = 0.f, eb = 0.f;
  ea = __builtin_amdgcn_fdot2(leaky2(x.v[0] + xr2[0]), att2[0], ea, false);
  eb = __builtin_amdgcn_fdot2(leaky2(x.v[1] + xr2[1]), att2[1], eb, false);
  ea = __builtin_amdgcn_fdot2(leaky2(x.v[2] + xr2[2]), att2[2], ea, false);
  eb = __builtin_amdgcn_fdot2(leaky2(x.v[3] + xr2[3]), att2[3], eb, false);
  return ea + eb;
}

template <int PAT>
__device__ __forceinline__ float swz(float x) {
  return __int_as_float(__builtin_amdgcn_ds_swizzle(__float_as_int(x), PAT));
}

__device__ __forceinline__ void red16x4(float& a, float& b, float& c, float& d) {
  a += swz<0x041F>(a); b += swz<0x041F>(b); c += swz<0x041F>(c); d += swz<0x041F>(d);
  a += swz<0x081F>(a); b += swz<0x081F>(b); c += swz<0x081F>(c); d += swz<0x081F>(d);
  a += swz<0x101F>(a); b += swz<0x101F>(b); c += swz<0x101F>(c); d += swz<0x101F>(d);
  a += swz<0x201F>(a); b += swz<0x201F>(b); c += swz<0x201F>(c); d += swz<0x201F>(d);
}
__device__ __forceinline__ float red16(float a) {
  a += swz<0x041F>(a);
  a += swz<0x081F>(a);
  a += swz<0x101F>(a);
  a += swz<0x201F>(a);
  return a;
}

// H heads; DG dst-groups/block; LGROW: log2 fp8 row stride; XROFF: xr byte off.
template <int H, int DG, bool RELU, bool WF32, int LGROW, int XROFF>
__global__ __launch_bounds__(H * DG * 64) void agg_kernel(
    const f16* __restrict__ h_in, const char* __restrict__ xp,
    const float* __restrict__ att, const float* __restrict__ bias,
    const int* __restrict__ csr, const int* __restrict__ rowstart,
    const int* __restrict__ perm,
    float* __restrict__ h_out, f16* __restrict__ hh) {
  __shared__ float headout[H][4 * DG][DH];
  __shared__ int nodes[4 * DG];
  const int wv = threadIdx.x >> 6;
  const int h = wv & (H - 1);
  const int dg = wv / H;
  const int lane = threadIdx.x & 63;
  const int g = lane >> 4, u = lane & 15;
  const int c0 = u * 8;
  if (threadIdx.x < 4 * DG) nodes[threadIdx.x] = perm[blockIdx.x * 4 * DG + threadIdx.x];
  const int dst = perm[blockIdx.x * 4 * DG + dg * 4 + g];
  const uint32 loff = (uint32)(h * DH + c0);  // fp8: 1 byte/elem

  f16x2 att2[4], xr2[4];
  {
    const float* ap = att + h * DH + c0;
    float a0[8];
    *(float4*)a0 = *(const float4*)ap;
    *(float4*)(a0 + 4) = *(const float4*)(ap + 4);
#pragma unroll
    for (int q = 0; q < 4; q++) att2[q] = f16x2{(f16)a0[2 * q], (f16)a0[2 * q + 1]};
    LV xrv = load8_f8(xp, ((uint32)dst << LGROW) + XROFF + loff);
#pragma unroll
    for (int q = 0; q < 4; q++) xr2[q] = xrv.v[q];
  }

  const int js = rowstart[dst], je = rowstart[dst + 1];

  // self loop seed
  float m, s;
  f16x2 acc[4];
  {
    LV xv = load8_f8(xp, ((uint32)dst << LGROW) + loff);
    m = red16(edot(xv, xr2, att2));
    s = 1.f;
#pragma unroll
    for (int q = 0; q < 4; q++) acc[q] = xv.v[q];
  }

  // 4-deep prefetch over CSR row (indices clamped to je-1)
  LV pf0, pf1, pf2, pf3;
  {
    int ja = js < je ? js : je - 1;
    int jb = js + 1 < je ? js + 1 : je - 1;
    int jc = js + 2 < je ? js + 2 : je - 1;
    int jd = js + 3 < je ? js + 3 : je - 1;
    if (js < je) {
      pf0 = load8_f8(xp, ((uint32)csr[ja] << LGROW) + loff);
      pf1 = load8_f8(xp, ((uint32)csr[jb] << LGROW) + loff);
      pf2 = load8_f8(xp, ((uint32)csr[jc] << LGROW) + loff);
      pf3 = load8_f8(xp, ((uint32)csr[jd] << LGROW) + loff);
    }
  }

  int j = js;
  for (; j + 3 < je; j += 4) {
    LV cv0 = pf0, cv1 = pf1, cv2 = pf2, cv3 = pf3;
    int ja = j + 4 < je ? j + 4 : je - 1;
    int jb = j + 5 < je ? j + 5 : je - 1;
    int jc = j + 6 < je ? j + 6 : je - 1;
    int jd = j + 7 < je ? j + 7 : je - 1;
    pf0 = load8_f8(xp, ((uint32)csr[ja] << LGROW) + loff);
    pf1 = load8_f8(xp, ((uint32)csr[jb] << LGROW) + loff);
    pf2 = load8_f8(xp, ((uint32)csr[jc] << LGROW) + loff);
    pf3 = load8_f8(xp, ((uint32)csr[jd] << LGROW) + loff);

    float e0 = edot(cv0, xr2, att2);
    float e1 = edot(cv1, xr2, att2);
    float e2 = edot(cv2, xr2, att2);
    float e3 = edot(cv3, xr2, att2);
    red16x4(e0, e1, e2, e3);

    float mn = fmaxf(fmaxf(fmaxf(m, e0), fmaxf(e1, e2)), e3);
    float a = __expf(m - mn);
    float p0 = __expf(e0 - mn);
    float p1 = __expf(e1 - mn);
    float p2 = __expf(e2 - mn);
    float p3 = __expf(e3 - mn);
    s = s * a + ((p0 + p1) + (p2 + p3));
    f16 ah = (f16)a, g0 = (f16)p0, g1 = (f16)p1, g2 = (f16)p2, g3 = (f16)p3;
    f16x2 a2 = {ah, ah}, q0 = {g0, g0}, q1 = {g1, g1}, q2 = {g2, g2}, q3 = {g3, g3};
#pragma unroll
    for (int q = 0; q < 4; q++) {
      f16x2 t = acc[q] * a2;
      t = cv0.v[q] * q0 + t;
      t = cv1.v[q] * q1 + t;
      t = cv2.v[q] * q2 + t;
      t = cv3.v[q] * q3 + t;
      acc[q] = t;
    }
    m = mn;
  }
  // tail: consume remaining prefetched edges one at a time
  for (int t = 0; j < je; j++, t++) {
    LV cv = (t == 0) ? pf0 : (t == 1) ? pf1 : pf2;
    float e = red16(edot(cv, xr2, att2));
    float mn = fmaxf(m, e);
    float a = __expf(m - mn);
    float p = __expf(e - mn);
    s = s * a + p;
    f16 ah = (f16)a, gh = (f16)p;
    f16x2 a2 = {ah, ah}, p2 = {gh, gh};
#pragma unroll
    for (int q = 0; q < 4; q++) acc[q] = acc[q] * a2 + cv.v[q] * p2;
    m = mn;
  }

  float inv = 1.f / s;
#pragma unroll
  for (int q = 0; q < 4; q++) {
    headout[h][dg * 4 + g][c0 + 2 * q] = (float)acc[q][0] * inv;
    headout[h][dg * 4 + g][c0 + 2 * q + 1] = (float)acc[q][1] * inv;
  }
  __syncthreads();
  for (int t = threadIdx.x; t < 4 * DG * DH; t += H * DG * 64) {
    int d = t >> 7, c = t & 127;
    float sum = 0.f;
#pragma unroll
    for (int q = 0; q < H; q++) sum += headout[q][d][c];
    float r = sum * (1.f / H) + bias[c];
    if (RELU) r = fmaxf(r, 0.f);
    int node = nodes[d];
    float o = r + (float)h_in[(size_t)node * DH + c];
    if (WF32) h_out[(size_t)node * DH + c] = o;
    else hh[(size_t)node * DH + c] = (f16)o;
  }
}

extern "C" void kernel_launch(void* const* d_in, const int* in_sizes, int n_in,
                              void* d_out, int out_size, void* d_ws, size_t ws_size,
                              hipStream_t stream) {
  const float* x = (const float*)d_in[0];
  const int* ei = (const int*)d_in[1];
  const float* Wl1 = (const float*)d_in[2];
  const float* Wr1 = (const float*)d_in[3];
  const float* att1 = (const float*)d_in[4];
  const float* b1 = (const float*)d_in[5];
  const float* Wl2 = (const float*)d_in[6];
  const float* Wr2 = (const float*)d_in[7];
  const float* att2 = (const float*)d_in[8];
  const float* b2 = (const float*)d_in[9];
  const float* Wl3 = (const float*)d_in[10];
  const float* Wr3 = (const float*)d_in[11];
  const float* att3 = (const float*)d_in[12];
  const float* b3 = (const float*)d_in[13];
  float* out = (float*)d_out;

  char* p = (char*)d_ws;
  u8* xl8  = (u8*)p;  p += (size_t)NN * 2048;   // fp8 xl|xr (all layers)
  f16* xh  = (f16*)p; p += (size_t)NN * DH * 2;
  f16* h1h = (f16*)p; p += (size_t)NN * DH * 2;
  f16* h2h = (f16*)p; p += (size_t)NN * DH * 2;
  f16* WT1 = (f16*)p; p += (size_t)2048 * 128 * 2;
  f16* WT2 = (f16*)p; p += (size_t)2048 * 128 * 2;
  f16* WT3 = (f16*)p; p += (size_t)1024 * 128 * 2;
  int* deg      = (int*)p; p += (size_t)NN * 4;
  int* cursor   = (int*)p; p += (size_t)NN * 4;
  int* rowstart = (int*)p; p += (size_t)(NN + 1) * 4;
  int* perm     = (int*)p; p += (size_t)NN * 4;
  int* bsum     = (int*)p; p += (size_t)32 * 4;
  int* ghist    = (int*)p; p += (size_t)20 * 64 * 4;
  int* csr      = (int*)p;

  const int* esrc = ei;
  const int* edst = ei + NE;

  const int nbc = (NN + 1023) / 1024;  // 20 CSR-build blocks

  hipMemsetAsync(deg, 0, sizeof(int) * 2 * NN, stream);  // deg + cursor
  prep_kernel<<<NB_CONV + 6 * 128, 256, 0, stream>>>(
      x, xh, NN * DH / 4, edst, deg, NE,
      Wl1, Wr1, Wl2, Wr2, Wl3, Wr3,
      WT1, WT1 + (size_t)1024 * 128, WT2, WT2 + (size_t)1024 * 128,
      WT3, WT3 + (size_t)512 * 128);
  csr_p1<<<nbc, 1024, 0, stream>>>(deg, rowstart, bsum, ghist, NN);
  csr_p3<<<nbc, 1024, 0, stream>>>(deg, rowstart, bsum, ghist, perm, NN, nbc);
  scatter_kernel<<<(NE + 255) / 256, 256, 0, stream>>>(esrc, edst, rowstart, cursor, csr, NE);

  const int nx = (NN + 127) / 128;  // 157
  const int ngemm1 = nx * 16;       // 2512
  const int nwb = NWR / 4;          // 1024 wave-per-row sort blocks
  const int nsub = ((NN - NWR) * 16 + 255) / 256;  // 994 subgroup sort blocks

  // layer 1: [sort(wave-rows) | sort(subgroups) | gemm1]
  gemm_sort_kernel<16><<<nwb + nsub + ngemm1, 256, 0, stream>>>(
      xh, WT1, xl8, NN, nwb, nsub, rowstart, csr, perm, NN);
  agg_kernel<8, 1, true, false, 11, 1024><<<NN / 4, 512, 0, stream>>>(
      xh, (const char*)xl8, att1, b1, csr, rowstart, perm, nullptr, h1h);
  // layer 2
  gemm_f8<16><<<nx * 16, 256, 0, stream>>>(h1h, WT2, xl8, NN);
  agg_kernel<8, 1, true, false, 11, 1024><<<NN / 4, 512, 0, stream>>>(
      h1h, (const char*)xl8, att2, b2, csr, rowstart, perm, nullptr, h2h);
  // layer 3: fp8 rows 1024 B (xl 0-511 | xr 512-1023), f32 output + residual
  gemm_f8<8><<<nx * 8, 256, 0, stream>>>(h2h, WT3, xl8, NN);
  agg_kernel<4, 2, false, true, 10, 512><<<NN / 8, 512, 0, stream>>>(
      h2h, (const char*)xl8, att3, b3, csr, rowstart, perm, out, nullptr);
}